// Round 1
// baseline (1136.898 us; speedup 1.0000x reference)
//
#include <hip/hip_runtime.h>
#include <stdint.h>

#define NB 4096
#define NT 48
#define NF 225
#define NH 128
#define NG 512   // 4*H
#define NCLS 100

typedef __attribute__((ext_vector_type(8))) short v8s;
typedef __attribute__((ext_vector_type(4))) float v4f;

__device__ __forceinline__ unsigned short f2bf(float f) {
    union { float f; unsigned u; } v; v.f = f;
    return (unsigned short)((v.u + 0x7FFFu + ((v.u >> 16) & 1u)) >> 16);
}
__device__ __forceinline__ float bf2f(unsigned short h) {
    union { unsigned u; float f; } v; v.u = ((unsigned)h) << 16;
    return v.f;
}
__device__ __forceinline__ float fsig(float x) {
    return __builtin_amdgcn_rcpf(1.f + __expf(-x));
}
__device__ __forceinline__ float ftanh(float x) {
    return 2.f * __builtin_amdgcn_rcpf(1.f + __expf(-2.f * x)) - 1.f;
}

// ---------------------------------------------------------------------------
// Kernel A: xg[dir][tt][b][512] = x[b][tx] @ w_ih^T + (b_ih + b_hh), bf16 MFMA
// 128x128 tile, K=225 padded to 2 halves of 128.
// ---------------------------------------------------------------------------
__global__ __launch_bounds__(256, 2) void k_gemm_xg(
    const float* __restrict__ x,
    const float* __restrict__ wih_f, const float* __restrict__ wih_b,
    const float* __restrict__ bih_f, const float* __restrict__ bhh_f,
    const float* __restrict__ bih_b, const float* __restrict__ bhh_b,
    float* __restrict__ xg, int t0, int tc)
{
    __shared__ __attribute__((aligned(16))) unsigned short lsA[128 * 128];
    __shared__ __attribute__((aligned(16))) unsigned short lsB[128 * 128];

    const int tid = threadIdx.x;
    const int ntile = blockIdx.x;          // 0..3
    const int btile = blockIdx.y;          // 0..31
    const int dir = blockIdx.z / tc;
    const int tt  = blockIdx.z % tc;
    const int t   = t0 + tt;
    const int tx  = dir ? (NT - 1 - t) : t;

    const float* wih = dir ? wih_b : wih_f;
    const float* bih = dir ? bih_b : bih_f;
    const float* bhh = dir ? bhh_b : bhh_f;

    const int lane = tid & 63;
    const int wid  = tid >> 6;
    const int wm   = wid >> 1;
    const int wn   = wid & 1;
    const int l15  = lane & 15;
    const int grp  = lane >> 4;

    const v4f vz = {0.f, 0.f, 0.f, 0.f};
    v4f acc[4][4];
#pragma unroll
    for (int i = 0; i < 4; ++i)
#pragma unroll
        for (int j = 0; j < 4; ++j) acc[i][j] = vz;

    for (int kh = 0; kh < 2; ++kh) {
        if (kh) __syncthreads();
        // stage A and B tiles (bf16, XOR-swizzled rows of 256B)
        for (int i = tid; i < 128 * 32; i += 256) {
            const int m  = i >> 5;
            const int kk = (i & 31) << 2;
            const int kg = (kh << 7) + kk;
            const float* xr = x + ((size_t)(btile * 128 + m) * NT + tx) * NF;
            const float* wr = wih + (size_t)(ntile * 128 + m) * NF;
            float a0 = (kg + 0 < NF) ? xr[kg + 0] : 0.f;
            float a1 = (kg + 1 < NF) ? xr[kg + 1] : 0.f;
            float a2 = (kg + 2 < NF) ? xr[kg + 2] : 0.f;
            float a3 = (kg + 3 < NF) ? xr[kg + 3] : 0.f;
            float b0 = (kg + 0 < NF) ? wr[kg + 0] : 0.f;
            float b1 = (kg + 1 < NF) ? wr[kg + 1] : 0.f;
            float b2 = (kg + 2 < NF) ? wr[kg + 2] : 0.f;
            float b3 = (kg + 3 < NF) ? wr[kg + 3] : 0.f;
            ushort4 av = make_ushort4(f2bf(a0), f2bf(a1), f2bf(a2), f2bf(a3));
            ushort4 bv = make_ushort4(f2bf(b0), f2bf(b1), f2bf(b2), f2bf(b3));
            const int byo = (m << 8) + (((kk << 1)) ^ ((m & 7) << 4));
            *(ushort4*)((char*)lsA + byo) = av;
            *(ushort4*)((char*)lsB + byo) = bv;
        }
        __syncthreads();
#pragma unroll
        for (int ks = 0; ks < 4; ++ks) {
            v8s af[4], bfr[4];
#pragma unroll
            for (int mt = 0; mt < 4; ++mt) {
                const int row = wm * 64 + mt * 16 + l15;
                const int byo = (row << 8) + (((ks << 6) + (grp << 4)) ^ ((row & 7) << 4));
                af[mt] = *(const v8s*)((const char*)lsA + byo);
            }
#pragma unroll
            for (int nt = 0; nt < 4; ++nt) {
                const int row = wn * 64 + nt * 16 + l15;
                const int byo = (row << 8) + (((ks << 6) + (grp << 4)) ^ ((row & 7) << 4));
                bfr[nt] = *(const v8s*)((const char*)lsB + byo);
            }
#pragma unroll
            for (int mt = 0; mt < 4; ++mt)
#pragma unroll
                for (int nt = 0; nt < 4; ++nt)
                    acc[mt][nt] = __builtin_amdgcn_mfma_f32_16x16x32_bf16(
                        af[mt], bfr[nt], acc[mt][nt], 0, 0, 0);
        }
    }

    // epilogue: + (b_ih + b_hh), store fp32
    const int colbase = ntile * 128 + wn * 64;
    float bias[4];
#pragma unroll
    for (int nt = 0; nt < 4; ++nt) {
        const int n = colbase + nt * 16 + l15;
        bias[nt] = bih[n] + bhh[n];
    }
    float* op = xg + ((size_t)(dir * tc + tt) * NB) * NG;
#pragma unroll
    for (int mt = 0; mt < 4; ++mt) {
#pragma unroll
        for (int r = 0; r < 4; ++r) {
            const int m = btile * 128 + wm * 64 + mt * 16 + (grp << 2) + r;
#pragma unroll
            for (int nt = 0; nt < 4; ++nt)
                op[(size_t)m * NG + colbase + nt * 16 + l15] = acc[mt][nt][r] + bias[nt];
        }
    }
}

// ---------------------------------------------------------------------------
// Kernel B: LSTM scan over tc steps. 8 waves = 4 gates x 2 row-halves,
// 32 batch rows/block. whh as persistent B-fragments in VGPRs.
// ---------------------------------------------------------------------------
__global__ __launch_bounds__(512) void k_scan(
    const float* __restrict__ xg,
    const float* __restrict__ whh_f, const float* __restrict__ whh_b,
    unsigned short* __restrict__ h_state,  // [2][NB][128] bf16
    float* __restrict__ c_state,           // [2][NB][128]
    float* __restrict__ hsum,              // [2][NB][128]
    int tc, int first)
{
    __shared__ __attribute__((aligned(16))) unsigned short h_lds[32 * 128];
    __shared__ float exch[4][32][129];

    const int tid   = threadIdx.x;
    const int btile = blockIdx.x;     // rows btile*32..+32
    const int dir   = blockIdx.y;
    const int lane  = tid & 63;
    const int wid   = tid >> 6;       // 0..7
    const int gate  = wid >> 1;       // 0=i 1=f 2=g 3=o
    const int half  = wid & 1;
    const int l15   = lane & 15;
    const int grp   = lane >> 4;
    const int rb    = btile * 32;

    const float* whh = dir ? whh_b : whh_f;

    // persistent B-fragments: B[k][n] = whh[n][k]
    v8s bw[8][4];
#pragma unroll
    for (int nt = 0; nt < 8; ++nt) {
        const int n = gate * 128 + nt * 16 + l15;
#pragma unroll
        for (int ks = 0; ks < 4; ++ks) {
            const float* p = whh + (size_t)n * NH + (ks << 5) + (grp << 3);
            v8s v;
#pragma unroll
            for (int i = 0; i < 8; ++i) v[i] = (short)f2bf(p[i]);
            bw[nt][ks] = v;
        }
    }

    float creg[4][2], hsreg[4][2];
    if (first) {
#pragma unroll
        for (int rr = 0; rr < 4; ++rr)
#pragma unroll
            for (int jj = 0; jj < 2; ++jj) { creg[rr][jj] = 0.f; hsreg[rr][jj] = 0.f; }
        for (int i = tid; i < 32 * 128; i += 512) h_lds[i] = 0;
    } else {
#pragma unroll
        for (int rr = 0; rr < 4; ++rr)
#pragma unroll
            for (int jj = 0; jj < 2; ++jj) {
                const size_t idx = ((size_t)dir * NB + rb + wid * 4 + rr) * NH + (jj << 6) + lane;
                creg[rr][jj]  = c_state[idx];
                hsreg[rr][jj] = hsum[idx];
            }
        for (int i = tid; i < 32 * 128; i += 512) {
            const int r = i >> 7, j = i & 127;
            const int byo = (r << 8) + (((j << 1)) ^ ((r & 7) << 4));
            *(unsigned short*)((char*)h_lds + byo) =
                h_state[((size_t)dir * NB + rb + r) * NH + j];
        }
    }
    __syncthreads();

    for (int tt = 0; tt < tc; ++tt) {
        const float* xp = xg + ((size_t)(dir * tc + tt) * NB + rb) * NG;
        // acc initialized with xg (C-operand of MFMA)
        v4f acc[8];
#pragma unroll
        for (int nt = 0; nt < 8; ++nt) {
            const int n = gate * 128 + nt * 16 + l15;
#pragma unroll
            for (int r = 0; r < 4; ++r) {
                const int m = half * 16 + (grp << 2) + r;
                acc[nt][r] = xp[(size_t)m * NG + n];
            }
        }
        if (!(first && tt == 0)) {
            v8s af[4];
#pragma unroll
            for (int ks = 0; ks < 4; ++ks) {
                const int row = half * 16 + l15;
                const int byo = (row << 8) + (((ks << 6) + (grp << 4)) ^ ((row & 7) << 4));
                af[ks] = *(const v8s*)((const char*)h_lds + byo);
            }
#pragma unroll
            for (int ks = 0; ks < 4; ++ks)
#pragma unroll
                for (int nt = 0; nt < 8; ++nt)
                    acc[nt] = __builtin_amdgcn_mfma_f32_16x16x32_bf16(
                        af[ks], bw[nt][ks], acc[nt], 0, 0, 0);
        }
        // activations -> exchange
#pragma unroll
        for (int nt = 0; nt < 8; ++nt) {
#pragma unroll
            for (int r = 0; r < 4; ++r) {
                const float pre = acc[nt][r];
                const float v = (gate == 2) ? ftanh(pre) : fsig(pre);
                exch[gate][half * 16 + (grp << 2) + r][nt * 16 + l15] = v;
            }
        }
        __syncthreads();
        // c,h update: wave wid owns rows wid*4..+4, lane owns j={lane, lane+64}
#pragma unroll
        for (int rr = 0; rr < 4; ++rr) {
            const int rl = wid * 4 + rr;
#pragma unroll
            for (int jj = 0; jj < 2; ++jj) {
                const int j = (jj << 6) + lane;
                const float iv = exch[0][rl][j];
                const float fv = exch[1][rl][j];
                const float gv = exch[2][rl][j];
                const float ov = exch[3][rl][j];
                const float c = fv * creg[rr][jj] + iv * gv;
                creg[rr][jj] = c;
                const float h = ov * ftanh(c);
                hsreg[rr][jj] += h;
                const int byo = (rl << 8) + (((j << 1)) ^ ((rl & 7) << 4));
                *(unsigned short*)((char*)h_lds + byo) = f2bf(h);
            }
        }
        __syncthreads();
    }

    // persist states
#pragma unroll
    for (int rr = 0; rr < 4; ++rr)
#pragma unroll
        for (int jj = 0; jj < 2; ++jj) {
            const size_t idx = ((size_t)dir * NB + rb + wid * 4 + rr) * NH + (jj << 6) + lane;
            c_state[idx] = creg[rr][jj];
            hsum[idx]    = hsreg[rr][jj];
        }
    for (int i = tid; i < 32 * 128; i += 512) {
        const int r = i >> 7, j = i & 127;
        const int byo = (r << 8) + (((j << 1)) ^ ((r & 7) << 4));
        h_state[((size_t)dir * NB + rb + r) * NH + j] =
            *(const unsigned short*)((const char*)h_lds + byo);
    }
}

// ---------------------------------------------------------------------------
// Kernel C: pooled = hsum/T ; h1 = relu(pooled@fc1_w^T+b) ; out = h1@fc2_w^T+b
// 16 rows/block, 128 threads.
// ---------------------------------------------------------------------------
__global__ __launch_bounds__(128) void k_head(
    const float* __restrict__ hsum,
    const float* __restrict__ fc1w, const float* __restrict__ fc1b,
    const float* __restrict__ fc2w, const float* __restrict__ fc2b,
    float* __restrict__ out)
{
    __shared__ __attribute__((aligned(16))) float pooled[16][256];
    __shared__ __attribute__((aligned(16))) float h1s[16][128];
    __shared__ __attribute__((aligned(16))) char wbuf[65536];

    const int tid = threadIdx.x;
    const int rb  = blockIdx.x * 16;

    for (int i = tid; i < 16 * 256; i += 128) {
        const int r = i >> 8, c = i & 255;
        const float v = (c < 128)
            ? hsum[(size_t)(rb + r) * NH + c]
            : hsum[((size_t)NB + rb + r) * NH + (c - 128)];
        pooled[r][c] = v * (1.f / (float)NT);
    }
    // fc1_w as bf16, swizzled rows of 512B
    for (int i = tid; i < 128 * 64; i += 128) {
        const int j = i >> 6, kq = i & 63;
        const float4 v = *(const float4*)(fc1w + (size_t)j * 256 + (kq << 2));
        ushort4 pv = make_ushort4(f2bf(v.x), f2bf(v.y), f2bf(v.z), f2bf(v.w));
        const int byo = (j << 9) + (((kq << 3)) ^ (((j >> 3) & 7) << 4));
        *(ushort4*)(wbuf + byo) = pv;
    }
    __syncthreads();

    const int rgrp = tid >> 4;     // 0..7 -> rows rgrp*2..+2
    const int joct = tid & 15;     // 0..15 -> j = joct*8..+8
    const int r0 = rgrp * 2;
    const int j0 = joct * 8;

    float a1[2][8];
#pragma unroll
    for (int rr = 0; rr < 2; ++rr)
#pragma unroll
        for (int jo = 0; jo < 8; ++jo) a1[rr][jo] = 0.f;

    for (int kc = 0; kc < 32; ++kc) {
        const int k = kc << 3;
        float pv[2][8];
#pragma unroll
        for (int rr = 0; rr < 2; ++rr) {
            const float4 pa = *(const float4*)&pooled[r0 + rr][k];
            const float4 pb = *(const float4*)&pooled[r0 + rr][k + 4];
            pv[rr][0] = pa.x; pv[rr][1] = pa.y; pv[rr][2] = pa.z; pv[rr][3] = pa.w;
            pv[rr][4] = pb.x; pv[rr][5] = pb.y; pv[rr][6] = pb.z; pv[rr][7] = pb.w;
        }
#pragma unroll
        for (int jo = 0; jo < 8; ++jo) {
            const int j = j0 + jo;
            const int byo = (j << 9) + (((k << 1)) ^ (((j >> 3) & 7) << 4));
            const v8s wv = *(const v8s*)(wbuf + byo);
#pragma unroll
            for (int i = 0; i < 8; ++i) {
                const float wf = bf2f((unsigned short)wv[i]);
#pragma unroll
                for (int rr = 0; rr < 2; ++rr)
                    a1[rr][jo] += pv[rr][i] * wf;
            }
        }
    }
#pragma unroll
    for (int rr = 0; rr < 2; ++rr)
#pragma unroll
        for (int jo = 0; jo < 8; ++jo) {
            const int j = j0 + jo;
            const float v = a1[rr][jo] + fc1b[j];
            h1s[r0 + rr][j] = v > 0.f ? v : 0.f;
        }
    __syncthreads();

    // fc2_w fp32, swizzled rows of 512B (reuse wbuf)
    for (int i = tid; i < 100 * 32; i += 128) {
        const int j = i >> 5, kq = i & 31;
        const float4 v = *(const float4*)(fc2w + (size_t)j * 128 + (kq << 2));
        const int byo = (j << 9) + (((kq << 4)) ^ (((j >> 3) & 7) << 4));
        *(float4*)(wbuf + byo) = v;
    }
    __syncthreads();

    if (j0 < 100) {
        float a2[2][8];
#pragma unroll
        for (int rr = 0; rr < 2; ++rr)
#pragma unroll
            for (int jo = 0; jo < 8; ++jo) a2[rr][jo] = 0.f;

        for (int kc = 0; kc < 16; ++kc) {
            const int k = kc << 3;
            float hv[2][8];
#pragma unroll
            for (int rr = 0; rr < 2; ++rr) {
                const float4 ha = *(const float4*)&h1s[r0 + rr][k];
                const float4 hb = *(const float4*)&h1s[r0 + rr][k + 4];
                hv[rr][0] = ha.x; hv[rr][1] = ha.y; hv[rr][2] = ha.z; hv[rr][3] = ha.w;
                hv[rr][4] = hb.x; hv[rr][5] = hb.y; hv[rr][6] = hb.z; hv[rr][7] = hb.w;
            }
#pragma unroll
            for (int jo = 0; jo < 8; ++jo) {
                const int j = j0 + jo;
                if (j < 100) {
                    const int sw = ((j >> 3) & 7) << 4;
                    const float4 wa = *(const float4*)(wbuf + (j << 9) + (((k << 2)) ^ sw));
                    const float4 wb = *(const float4*)(wbuf + (j << 9) + ((((k + 4) << 2)) ^ sw));
#pragma unroll
                    for (int rr = 0; rr < 2; ++rr) {
                        a2[rr][jo] += hv[rr][0] * wa.x + hv[rr][1] * wa.y
                                    + hv[rr][2] * wa.z + hv[rr][3] * wa.w
                                    + hv[rr][4] * wb.x + hv[rr][5] * wb.y
                                    + hv[rr][6] * wb.z + hv[rr][7] * wb.w;
                    }
                }
            }
        }
#pragma unroll
        for (int rr = 0; rr < 2; ++rr)
#pragma unroll
            for (int jo = 0; jo < 8; ++jo) {
                const int j = j0 + jo;
                if (j < 100)
                    out[(size_t)(rb + r0 + rr) * NCLS + j] = a2[rr][jo] + fc2b[j];
            }
    }
}

// ---------------------------------------------------------------------------
extern "C" void kernel_launch(void* const* d_in, const int* in_sizes, int n_in,
                              void* d_out, int out_size, void* d_ws, size_t ws_size,
                              hipStream_t stream)
{
    (void)in_sizes; (void)n_in; (void)out_size;
    const float* x    = (const float*)d_in[0];
    const float* wihf = (const float*)d_in[1];
    const float* whhf = (const float*)d_in[2];
    const float* bihf = (const float*)d_in[3];
    const float* bhhf = (const float*)d_in[4];
    const float* wihb = (const float*)d_in[5];
    const float* whhb = (const float*)d_in[6];
    const float* bihb = (const float*)d_in[7];
    const float* bhhb = (const float*)d_in[8];
    const float* fc1w = (const float*)d_in[9];
    const float* fc1b = (const float*)d_in[10];
    const float* fc2w = (const float*)d_in[11];
    const float* fc2b = (const float*)d_in[12];
    float* out = (float*)d_out;

    char* ws = (char*)d_ws;
    float* c_state = (float*)ws;                                    // 4 MB
    float* hs      = (float*)(ws + (size_t)4 * 1024 * 1024);        // 4 MB
    unsigned short* h_state = (unsigned short*)(ws + (size_t)8 * 1024 * 1024); // 2 MB
    float* xgbuf   = (float*)(ws + (size_t)10 * 1024 * 1024);

    const size_t per_t = (size_t)2 * NB * NG * sizeof(float);       // 16 MB / step
    const size_t hdr = (size_t)10 * 1024 * 1024;
    size_t avail = ws_size > hdr ? ws_size - hdr : 0;
    int tcmax = (int)(avail / per_t);
    if (tcmax < 1) tcmax = 1;
    int Tc = tcmax >= 12 ? 12 : tcmax;   // 12 -> xg chunk ~201 MB, L3-resident

    int t0 = 0, first = 1;
    while (t0 < NT) {
        const int tc = (NT - t0 < Tc) ? (NT - t0) : Tc;
        dim3 g1(4, 32, 2 * tc);
        k_gemm_xg<<<g1, dim3(256), 0, stream>>>(
            x, wihf, wihb, bihf, bhhf, bihb, bhhb, xgbuf, t0, tc);
        dim3 g2(128, 2);
        k_scan<<<g2, dim3(512), 0, stream>>>(
            xgbuf, whhf, whhb, h_state, c_state, hs, tc, first);
        first = 0;
        t0 += tc;
    }
    k_head<<<dim3(256), dim3(128), 0, stream>>>(hs, fc1w, fc1b, fc2w, fc2b, out);
}

// Round 2
// 635.975 us; speedup vs baseline: 1.7876x; 1.7876x over previous
//
#include <hip/hip_runtime.h>
#include <stdint.h>

#define NB 4096
#define NT 48
#define NF 225
#define NH 128
#define NG 512   // 4*H
#define NK 256   // K padded 225->256
#define NCLS 100

typedef __attribute__((ext_vector_type(8))) _Float16 v8h;
typedef __attribute__((ext_vector_type(4))) _Float16 v4h;
typedef __attribute__((ext_vector_type(4))) float v4f;
typedef __attribute__((ext_vector_type(8))) unsigned short u16x8;

__device__ __forceinline__ float fsig(float x) {
    return __builtin_amdgcn_rcpf(1.f + __expf(-x));
}
__device__ __forceinline__ float ftanh(float x) {
    return 2.f * __builtin_amdgcn_rcpf(1.f + __expf(-2.f * x)) - 1.f;
}

// global -> LDS direct copy, 16B per lane. LDS dest must be wave-uniform base.
__device__ __forceinline__ void gld16(const void* g, void* l) {
    __builtin_amdgcn_global_load_lds(
        (const __attribute__((address_space(1))) void*)g,
        (__attribute__((address_space(3))) void*)l, 16, 0, 0);
}

// ---------------------------------------------------------------------------
// k_prep: one-time conversions.
//  xh[b][t][256]  fp16, zero-padded K, 16B-chunks XOR-pre-swizzled by (b&7)
//  wh[dir][512][256] fp16, pre-swizzled by (n&7)
//  whh_h[dir][512][128] fp16 linear
//  bsum[dir][512] = b_ih + b_hh (fp32)
// ---------------------------------------------------------------------------
#define NXB ((NB * NT) / 8)   // 24576 blocks for x
__global__ __launch_bounds__(256) void k_prep(
    const float* __restrict__ x,
    const float* __restrict__ wihf, const float* __restrict__ wihb,
    const float* __restrict__ whhf, const float* __restrict__ whhb,
    const float* __restrict__ bihf, const float* __restrict__ bhhf,
    const float* __restrict__ bihb, const float* __restrict__ bhhb,
    _Float16* __restrict__ xh, _Float16* __restrict__ wh,
    _Float16* __restrict__ whh_h, float* __restrict__ bsum)
{
    const int bid = blockIdx.x;
    const int tid = threadIdx.x;
    if (bid < NXB) {
        const int row = bid * 8 + (tid >> 5);      // b*48+t
        const int c   = tid & 31;                  // 16B chunk (8 halves)
        const float* src = x + (size_t)row * NF + c * 8;
        v8h hv;
#pragma unroll
        for (int i = 0; i < 8; ++i) {
            const int k = c * 8 + i;
            hv[i] = (k < NF) ? (_Float16)src[i] : (_Float16)0.f;
        }
        const int bkey = (row / NT) & 7;
        *(v8h*)(xh + (size_t)row * NK + ((c ^ bkey) << 3)) = hv;
    } else if (bid < NXB + 128) {
        const int r = (bid - NXB) * 8 + (tid >> 5);   // 0..1023
        const int c = tid & 31;
        const int dir = r >> 9, n = r & 511;
        const float* src = (dir ? wihb : wihf) + (size_t)n * NF + c * 8;
        v8h hv;
#pragma unroll
        for (int i = 0; i < 8; ++i) {
            const int k = c * 8 + i;
            hv[i] = (k < NF) ? (_Float16)src[i] : (_Float16)0.f;
        }
        const int key = n & 7;
        *(v8h*)(wh + (size_t)r * NK + ((c ^ key) << 3)) = hv;
    } else if (bid < NXB + 160) {
        const int base = (bid - NXB - 128) * 4096 + tid;   // whh: 131072 elems
#pragma unroll
        for (int s = 0; s < 16; ++s) {
            const int i = base + s * 256;
            whh_h[i] = (_Float16)((i < 65536) ? whhf[i] : whhb[i - 65536]);
        }
    } else {
        for (int i = tid; i < 1024; i += 256) {
            const int dir = i >> 9, n = i & 511;
            bsum[i] = dir ? (bihb[n] + bhhb[n]) : (bihf[n] + bhhf[n]);
        }
    }
}

// ---------------------------------------------------------------------------
// k_gemm: xg[dir*tc+tt][b][512] fp16 = xh[b][tx] @ wh[dir]^T + bsum
// 128x128 tile, K=256 in 2 halves, global_load_lds staging, XCD swizzle.
// ---------------------------------------------------------------------------
__global__ __launch_bounds__(256, 2) void k_gemm(
    const _Float16* __restrict__ xh, const _Float16* __restrict__ wh,
    const float* __restrict__ bsum, _Float16* __restrict__ xg,
    int t0, int tc)
{
    __shared__ __attribute__((aligned(16))) _Float16 lsA[128 * 128]; // 32KB
    __shared__ __attribute__((aligned(16))) _Float16 lsB[128 * 128]; // 32KB

    const int tid = threadIdx.x;
    // bijective XCD swizzle (nwg = 256*tc, always %8==0)
    const int nwg = gridDim.x;
    const int f = blockIdx.x;
    const int q = nwg >> 3;
    const int wgid = (f & 7) * q + (f >> 3);
    const int ntile = wgid & 3;
    const int btile = (wgid >> 2) & 31;
    const int z = wgid >> 7;
    const int dir = (z >= tc) ? 1 : 0;
    const int tt = z - dir * tc;
    const int t = t0 + tt;
    const int tx = dir ? (NT - 1 - t) : t;

    const int lane = tid & 63;
    const int w = tid >> 6;
    const int wm = w >> 1, wn = w & 1;
    const int l15 = lane & 15, grp = lane >> 4;
    const int lr = lane >> 4, lc = lane & 15;

    const v4f vz = {0.f, 0.f, 0.f, 0.f};
    v4f acc[4][4];
#pragma unroll
    for (int i = 0; i < 4; ++i)
#pragma unroll
        for (int j = 0; j < 4; ++j) acc[i][j] = vz;

#pragma unroll
    for (int kh = 0; kh < 2; ++kh) {
        // stage half kh: A 32KB + B 32KB via global_load_lds (pre-swizzled src)
#pragma unroll
        for (int j = 0; j < 8; ++j) {
            const int m = w * 32 + j * 4 + lr;
            const _Float16* ga = xh + ((size_t)(btile * 128 + m) * NT + tx) * NK
                                 + kh * 128 + lc * 8;
            gld16(ga, (char*)lsA + (w * 32 + j * 4) * 256);
            const _Float16* gb = wh + (size_t)(dir * NG + ntile * 128 + m) * NK
                                 + kh * 128 + lc * 8;
            gld16(gb, (char*)lsB + (w * 32 + j * 4) * 256);
        }
        __syncthreads();   // drains vmcnt before barrier (compiler semantics)
#pragma unroll
        for (int ks = 0; ks < 4; ++ks) {
            v8h af[4], bfr[4];
#pragma unroll
            for (int mt = 0; mt < 4; ++mt) {
                const int row = wm * 64 + mt * 16 + l15;
                af[mt] = *(const v8h*)((const char*)lsA + row * 256
                          + (((ks * 4 + grp) ^ (row & 7)) << 4));
            }
#pragma unroll
            for (int nt = 0; nt < 4; ++nt) {
                const int row = wn * 64 + nt * 16 + l15;
                bfr[nt] = *(const v8h*)((const char*)lsB + row * 256
                          + (((ks * 4 + grp) ^ (row & 7)) << 4));
            }
#pragma unroll
            for (int mt = 0; mt < 4; ++mt)
#pragma unroll
                for (int nt = 0; nt < 4; ++nt)
                    acc[mt][nt] = __builtin_amdgcn_mfma_f32_16x16x32_f16(
                        af[mt], bfr[nt], acc[mt][nt], 0, 0, 0);
        }
        __syncthreads();   // LDS reuse for next half / epilogue
    }

    // epilogue: +bias, fp16, repack via LDS for full-line global writes
    float bias[4];
#pragma unroll
    for (int nt = 0; nt < 4; ++nt)
        bias[nt] = bsum[dir * NG + ntile * 128 + wn * 64 + nt * 16 + l15];
#pragma unroll
    for (int mt = 0; mt < 4; ++mt)
#pragma unroll
        for (int nt = 0; nt < 4; ++nt)
#pragma unroll
            for (int r = 0; r < 4; ++r) {
                const int row = wm * 64 + mt * 16 + (grp << 2) + r;
                const int col = wn * 64 + nt * 16 + l15;
                lsA[row * 128 + col] = (_Float16)(acc[mt][nt][r] + bias[nt]);
            }
    __syncthreads();
    _Float16* orow = xg + ((size_t)(dir * tc + tt) * NB + btile * 128) * NG
                     + ntile * 128;
#pragma unroll
    for (int j = 0; j < 8; ++j) {
        const int idx = j * 256 + tid;
        const int rrow = idx >> 4, c16 = idx & 15;
        *(v8h*)(orow + (size_t)rrow * NG + c16 * 8) =
            *(const v8h*)(lsA + rrow * 128 + c16 * 8);
    }
}

// ---------------------------------------------------------------------------
// k_scan: LSTM recurrence, fp16 h/whh/xg, xg prefetched one step ahead.
// 8 waves = 4 gates x 2 row-halves, 32 batch rows/block.
// ---------------------------------------------------------------------------
__global__ __launch_bounds__(512) void k_scan(
    const _Float16* __restrict__ xg,
    const _Float16* __restrict__ whh_h,
    _Float16* __restrict__ h_state,   // [2][NB][128]
    float* __restrict__ c_state,      // [2][NB][128]
    float* __restrict__ hsum,         // [2][NB][128]
    int tc, int first)
{
    __shared__ __attribute__((aligned(16))) _Float16 h_lds[32 * 128];
    __shared__ float exch[4][32][129];

    const int tid   = threadIdx.x;
    const int btile = blockIdx.x;
    const int dir   = blockIdx.y;
    const int lane  = tid & 63;
    const int wid   = tid >> 6;
    const int gate  = wid >> 1;
    const int half  = wid & 1;
    const int l15   = lane & 15;
    const int grp   = lane >> 4;
    const int rb    = btile * 32;

    const _Float16* whh = whh_h + (size_t)dir * NG * NH;

    v8h bw[8][4];
#pragma unroll
    for (int nt = 0; nt < 8; ++nt)
#pragma unroll
        for (int ks = 0; ks < 4; ++ks)
            bw[nt][ks] = *(const v8h*)(whh +
                (size_t)(gate * 128 + nt * 16 + l15) * NH + ks * 32 + grp * 8);

    float creg[4][2], hsreg[4][2];
    if (first) {
#pragma unroll
        for (int rr = 0; rr < 4; ++rr)
#pragma unroll
            for (int jj = 0; jj < 2; ++jj) { creg[rr][jj] = 0.f; hsreg[rr][jj] = 0.f; }
        for (int i = tid; i < 32 * 128; i += 512) h_lds[i] = (_Float16)0.f;
    } else {
#pragma unroll
        for (int rr = 0; rr < 4; ++rr)
#pragma unroll
            for (int jj = 0; jj < 2; ++jj) {
                const size_t idx = ((size_t)dir * NB + rb + wid * 4 + rr) * NH + (jj << 6) + lane;
                creg[rr][jj]  = c_state[idx];
                hsreg[rr][jj] = hsum[idx];
            }
        for (int i = tid; i < 32 * 128; i += 512) {
            const int r = i >> 7, j = i & 127;
            const int byo = (r << 8) + (((j << 1)) ^ ((r & 7) << 4));
            *(_Float16*)((char*)h_lds + byo) =
                h_state[((size_t)dir * NB + rb + r) * NH + j];
        }
    }
    __syncthreads();

    auto loadxg = [&](int tt, float (&d)[8][4]) {
        const _Float16* p = xg
            + ((size_t)(dir * tc + tt) * NB + rb + half * 16 + (grp << 2)) * NG
            + gate * 128 + l15;
#pragma unroll
        for (int nt = 0; nt < 8; ++nt)
#pragma unroll
            for (int r = 0; r < 4; ++r)
                d[nt][r] = (float)p[(size_t)r * NG + nt * 16];
    };

    auto body = [&](int tt, float (&cur)[8][4], float (&nxt)[8][4]) {
        if (tt + 1 < tc) loadxg(tt + 1, nxt);   // prefetch across this step
        v4f acc[8];
#pragma unroll
        for (int nt = 0; nt < 8; ++nt)
#pragma unroll
            for (int r = 0; r < 4; ++r) acc[nt][r] = cur[nt][r];
        if (!(first && tt == 0)) {
            v8h af[4];
#pragma unroll
            for (int ks = 0; ks < 4; ++ks) {
                const int row = half * 16 + l15;
                af[ks] = *(const v8h*)((const char*)h_lds + (row << 8)
                          + (((ks * 4 + grp) ^ (row & 7)) << 4));
            }
#pragma unroll
            for (int ks = 0; ks < 4; ++ks)
#pragma unroll
                for (int nt = 0; nt < 8; ++nt)
                    acc[nt] = __builtin_amdgcn_mfma_f32_16x16x32_f16(
                        af[ks], bw[nt][ks], acc[nt], 0, 0, 0);
        }
#pragma unroll
        for (int nt = 0; nt < 8; ++nt)
#pragma unroll
            for (int r = 0; r < 4; ++r) {
                const float pre = acc[nt][r];
                const float v = (gate == 2) ? ftanh(pre) : fsig(pre);
                exch[gate][half * 16 + (grp << 2) + r][nt * 16 + l15] = v;
            }
        __syncthreads();
#pragma unroll
        for (int rr = 0; rr < 4; ++rr) {
            const int rl = wid * 4 + rr;
#pragma unroll
            for (int jj = 0; jj < 2; ++jj) {
                const int j = (jj << 6) + lane;
                const float iv = exch[0][rl][j];
                const float fv = exch[1][rl][j];
                const float gv = exch[2][rl][j];
                const float ov = exch[3][rl][j];
                const float c = fv * creg[rr][jj] + iv * gv;
                creg[rr][jj] = c;
                const float h = ov * ftanh(c);
                hsreg[rr][jj] += h;
                const int byo = (rl << 8) + (((j << 1)) ^ ((rl & 7) << 4));
                *(_Float16*)((char*)h_lds + byo) = (_Float16)h;
            }
        }
        __syncthreads();
    };

    float xa[8][4], xb[8][4];
    loadxg(0, xa);
    for (int tt = 0; tt < tc; tt += 2) {
        body(tt, xa, xb);
        if (tt + 1 < tc) body(tt + 1, xb, xa);
    }

#pragma unroll
    for (int rr = 0; rr < 4; ++rr)
#pragma unroll
        for (int jj = 0; jj < 2; ++jj) {
            const size_t idx = ((size_t)dir * NB + rb + wid * 4 + rr) * NH + (jj << 6) + lane;
            c_state[idx] = creg[rr][jj];
            hsum[idx]    = hsreg[rr][jj];
        }
    for (int i = tid; i < 32 * 128; i += 512) {
        const int r = i >> 7, j = i & 127;
        const int byo = (r << 8) + (((j << 1)) ^ ((r & 7) << 4));
        h_state[((size_t)dir * NB + rb + r) * NH + j] =
            *(const _Float16*)((const char*)h_lds + byo);
    }
}

// ---------------------------------------------------------------------------
// k_head: pooled = hsum/T ; h1 = relu(pooled@fc1_w^T+b) ; out = h1@fc2_w^T+b
// ---------------------------------------------------------------------------
__global__ __launch_bounds__(128) void k_head(
    const float* __restrict__ hsum,
    const float* __restrict__ fc1w, const float* __restrict__ fc1b,
    const float* __restrict__ fc2w, const float* __restrict__ fc2b,
    float* __restrict__ out)
{
    __shared__ __attribute__((aligned(16))) float pooled[16][256];
    __shared__ __attribute__((aligned(16))) float h1s[16][128];
    __shared__ __attribute__((aligned(16))) char wbuf[65536];

    const int tid = threadIdx.x;
    const int rb  = blockIdx.x * 16;

    for (int i = tid; i < 16 * 256; i += 128) {
        const int r = i >> 8, c = i & 255;
        const float v = (c < 128)
            ? hsum[(size_t)(rb + r) * NH + c]
            : hsum[((size_t)NB + rb + r) * NH + (c - 128)];
        pooled[r][c] = v * (1.f / (float)NT);
    }
    // fc1_w as fp16, swizzled rows of 512B
    for (int i = tid; i < 128 * 64; i += 128) {
        const int j = i >> 6, kq = i & 63;
        const float4 v = *(const float4*)(fc1w + (size_t)j * 256 + (kq << 2));
        v4h pv; pv[0] = (_Float16)v.x; pv[1] = (_Float16)v.y;
        pv[2] = (_Float16)v.z; pv[3] = (_Float16)v.w;
        const int byo = (j << 9) + (((kq << 3)) ^ (((j >> 3) & 7) << 4));
        *(v4h*)(wbuf + byo) = pv;
    }
    __syncthreads();

    const int rgrp = tid >> 4;
    const int joct = tid & 15;
    const int r0 = rgrp * 2;
    const int j0 = joct * 8;

    float a1[2][8];
#pragma unroll
    for (int rr = 0; rr < 2; ++rr)
#pragma unroll
        for (int jo = 0; jo < 8; ++jo) a1[rr][jo] = 0.f;

    for (int kc = 0; kc < 32; ++kc) {
        const int k = kc << 3;
        float pv[2][8];
#pragma unroll
        for (int rr = 0; rr < 2; ++rr) {
            const float4 pa = *(const float4*)&pooled[r0 + rr][k];
            const float4 pb = *(const float4*)&pooled[r0 + rr][k + 4];
            pv[rr][0] = pa.x; pv[rr][1] = pa.y; pv[rr][2] = pa.z; pv[rr][3] = pa.w;
            pv[rr][4] = pb.x; pv[rr][5] = pb.y; pv[rr][6] = pb.z; pv[rr][7] = pb.w;
        }
#pragma unroll
        for (int jo = 0; jo < 8; ++jo) {
            const int j = j0 + jo;
            const int byo = (j << 9) + (((k << 1)) ^ (((j >> 3) & 7) << 4));
            const v8h wv = *(const v8h*)(wbuf + byo);
#pragma unroll
            for (int i = 0; i < 8; ++i) {
                const float wf = (float)wv[i];
#pragma unroll
                for (int rr = 0; rr < 2; ++rr)
                    a1[rr][jo] += pv[rr][i] * wf;
            }
        }
    }
#pragma unroll
    for (int rr = 0; rr < 2; ++rr)
#pragma unroll
        for (int jo = 0; jo < 8; ++jo) {
            const int j = j0 + jo;
            const float v = a1[rr][jo] + fc1b[j];
            h1s[r0 + rr][j] = v > 0.f ? v : 0.f;
        }
    __syncthreads();

    for (int i = tid; i < 100 * 32; i += 128) {
        const int j = i >> 5, kq = i & 31;
        const float4 v = *(const float4*)(fc2w + (size_t)j * 128 + (kq << 2));
        const int byo = (j << 9) + (((kq << 4)) ^ (((j >> 3) & 7) << 4));
        *(float4*)(wbuf + byo) = v;
    }
    __syncthreads();

    if (j0 < 100) {
        float a2[2][8];
#pragma unroll
        for (int rr = 0; rr < 2; ++rr)
#pragma unroll
            for (int jo = 0; jo < 8; ++jo) a2[rr][jo] = 0.f;

        for (int kc = 0; kc < 16; ++kc) {
            const int k = kc << 3;
            float hv[2][8];
#pragma unroll
            for (int rr = 0; rr < 2; ++rr) {
                const float4 ha = *(const float4*)&h1s[r0 + rr][k];
                const float4 hb = *(const float4*)&h1s[r0 + rr][k + 4];
                hv[rr][0] = ha.x; hv[rr][1] = ha.y; hv[rr][2] = ha.z; hv[rr][3] = ha.w;
                hv[rr][4] = hb.x; hv[rr][5] = hb.y; hv[rr][6] = hb.z; hv[rr][7] = hb.w;
            }
#pragma unroll
            for (int jo = 0; jo < 8; ++jo) {
                const int j = j0 + jo;
                if (j < 100) {
                    const int sw = ((j >> 3) & 7) << 4;
                    const float4 wa = *(const float4*)(wbuf + (j << 9) + (((k << 2)) ^ sw));
                    const float4 wb = *(const float4*)(wbuf + (j << 9) + ((((k + 4) << 2)) ^ sw));
#pragma unroll
                    for (int rr = 0; rr < 2; ++rr) {
                        a2[rr][jo] += hv[rr][0] * wa.x + hv[rr][1] * wa.y
                                    + hv[rr][2] * wa.z + hv[rr][3] * wa.w
                                    + hv[rr][4] * wb.x + hv[rr][5] * wb.y
                                    + hv[rr][6] * wb.z + hv[rr][7] * wb.w;
                    }
                }
            }
        }
#pragma unroll
        for (int rr = 0; rr < 2; ++rr)
#pragma unroll
            for (int jo = 0; jo < 8; ++jo) {
                const int j = j0 + jo;
                if (j < 100)
                    out[(size_t)(rb + r0 + rr) * NCLS + j] = a2[rr][jo] + fc2b[j];
            }
    }
}

// ---------------------------------------------------------------------------
extern "C" void kernel_launch(void* const* d_in, const int* in_sizes, int n_in,
                              void* d_out, int out_size, void* d_ws, size_t ws_size,
                              hipStream_t stream)
{
    (void)in_sizes; (void)n_in; (void)out_size;
    const float* x    = (const float*)d_in[0];
    const float* wihf = (const float*)d_in[1];
    const float* whhf = (const float*)d_in[2];
    const float* bihf = (const float*)d_in[3];
    const float* bhhf = (const float*)d_in[4];
    const float* wihb = (const float*)d_in[5];
    const float* whhb = (const float*)d_in[6];
    const float* bihb = (const float*)d_in[7];
    const float* bhhb = (const float*)d_in[8];
    const float* fc1w = (const float*)d_in[9];
    const float* fc1b = (const float*)d_in[10];
    const float* fc2w = (const float*)d_in[11];
    const float* fc2b = (const float*)d_in[12];
    float* out = (float*)d_out;

    char* ws = (char*)d_ws;
    float*     c_state = (float*)ws;                                     // 4 MB
    float*     hs      = (float*)(ws + (size_t)4 * 1024 * 1024);         // 4 MB
    _Float16*  h_state = (_Float16*)(ws + (size_t)8 * 1024 * 1024);      // 2 MB
    size_t off = (size_t)10 * 1024 * 1024;
    _Float16*  xh    = (_Float16*)(ws + off); off += (size_t)NB * NT * NK * 2;  // 100.7 MB
    _Float16*  wh    = (_Float16*)(ws + off); off += (size_t)2 * NG * NK * 2;   // 0.5 MB
    _Float16*  whh_h = (_Float16*)(ws + off); off += (size_t)2 * NG * NH * 2;   // 0.25 MB
    float*     bsum  = (float*)(ws + off);    off += 1024 * 4;
    _Float16*  xgbuf = (_Float16*)(ws + off);

    const size_t per_t = (size_t)2 * NB * NG * 2;   // 8 MB per timestep (fp16)
    size_t avail = ws_size > off ? ws_size - off : 0;
    int tcmax = (int)(avail / per_t);
    if (tcmax < 1) tcmax = 1;
    int Tc = tcmax >= 12 ? 12 : tcmax;

    k_prep<<<dim3(NXB + 161), dim3(256), 0, stream>>>(
        x, wihf, wihb, whhf, whhb, bihf, bhhf, bihb, bhhb, xh, wh, whh_h, bsum);

    int t0 = 0, first = 1;
    while (t0 < NT) {
        const int tc = (NT - t0 < Tc) ? (NT - t0) : Tc;
        k_gemm<<<dim3(256 * tc), dim3(256), 0, stream>>>(xh, wh, bsum, xgbuf, t0, tc);
        k_scan<<<dim3(128, 2), dim3(512), 0, stream>>>(
            xgbuf, whh_h, h_state, c_state, hs, tc, first);
        first = 0;
        t0 += tc;
    }
    k_head<<<dim3(256), dim3(128), 0, stream>>>(hs, fc1w, fc1b, fc2w, fc2b, out);
}

// Round 3
// 494.439 us; speedup vs baseline: 2.2994x; 1.2863x over previous
//
#include <hip/hip_runtime.h>
#include <stdint.h>

#define NB 4096
#define NT 48
#define NF 225
#define NH 128
#define NG 512   // 4*H
#define NK 256   // K padded 225->256
#define NCLS 100

typedef __attribute__((ext_vector_type(8))) _Float16 v8h;
typedef __attribute__((ext_vector_type(4))) _Float16 v4h;
typedef __attribute__((ext_vector_type(4))) float v4f;

__device__ __forceinline__ float fsig(float x) {
    return __builtin_amdgcn_rcpf(1.f + __expf(-x));
}
__device__ __forceinline__ float ftanh(float x) {
    return 2.f * __builtin_amdgcn_rcpf(1.f + __expf(-2.f * x)) - 1.f;
}

// global -> LDS direct copy, 16B per lane (dest = base + lane*16).
__device__ __forceinline__ void gld16(const void* g, void* l) {
    __builtin_amdgcn_global_load_lds(
        (const __attribute__((address_space(1))) void*)g,
        (__attribute__((address_space(3))) void*)l, 16, 0, 0);
}

// ---------------------------------------------------------------------------
// k_prep:
//  xh[t][b][256] fp16, zero-padded K, 16B chunks XOR-swizzled by (b&7)
//  wh[dir][512][256] fp16, chunk-swizzled by (n&7)
//  whh_h[dir][512][128] fp16 linear
//  bsum[dir][512] = b_ih + b_hh (fp32)
// x-part: block = one b-row; coalesced float4 reads of contiguous 43200B,
// LDS bounce, packed v8h scatter-writes (t-major).
// ---------------------------------------------------------------------------
__global__ __launch_bounds__(256) void k_prep(
    const float* __restrict__ x,
    const float* __restrict__ wihf, const float* __restrict__ wihb,
    const float* __restrict__ whhf, const float* __restrict__ whhb,
    const float* __restrict__ bihf, const float* __restrict__ bhhf,
    const float* __restrict__ bihb, const float* __restrict__ bhhb,
    _Float16* __restrict__ xh, _Float16* __restrict__ wh,
    _Float16* __restrict__ whh_h, float* __restrict__ bsum)
{
    __shared__ __attribute__((aligned(16))) _Float16 ls[NT * NF + 16];
    const int bid = blockIdx.x;
    const int tid = threadIdx.x;

    if (bid < NB) {
        const float* src = x + (size_t)bid * (NT * NF);   // 43200B, 16B-aligned
        for (int i = tid; i < (NT * NF) / 4; i += 256) {  // 2700 float4
            const float4 v = ((const float4*)src)[i];
            v4h hv; hv[0] = (_Float16)v.x; hv[1] = (_Float16)v.y;
            hv[2] = (_Float16)v.z; hv[3] = (_Float16)v.w;
            *(v4h*)(ls + i * 4) = hv;
        }
        __syncthreads();
        const int key = bid & 7;
        for (int task = tid; task < NT * 32; task += 256) {
            const int t = task >> 5, c = task & 31;
            v8h hv;
#pragma unroll
            for (int e = 0; e < 8; ++e) {
                const int k = c * 8 + e;
                hv[e] = (k < NF) ? ls[t * NF + k] : (_Float16)0.f;
            }
            *(v8h*)(xh + ((size_t)t * NB + bid) * NK + ((c ^ key) << 3)) = hv;
        }
    } else if (bid < NB + 128) {
        const int r = (bid - NB) * 8 + (tid >> 5);   // 0..1023
        const int c = tid & 31;
        const int dir = r >> 9, n = r & 511;
        const float* src = (dir ? wihb : wihf) + (size_t)n * NF + c * 8;
        v8h hv;
#pragma unroll
        for (int i = 0; i < 8; ++i) {
            const int k = c * 8 + i;
            hv[i] = (k < NF) ? (_Float16)src[i] : (_Float16)0.f;
        }
        const int key = n & 7;
        *(v8h*)(wh + (size_t)r * NK + ((c ^ key) << 3)) = hv;
    } else if (bid < NB + 160) {
        const int base = (bid - NB - 128) * 4096 + tid;   // whh: 131072 elems
#pragma unroll
        for (int s = 0; s < 16; ++s) {
            const int i = base + s * 256;
            whh_h[i] = (_Float16)((i < 65536) ? whhf[i] : whhb[i - 65536]);
        }
    } else {
        for (int i = tid; i < 1024; i += 256) {
            const int dir = i >> 9, n = i & 511;
            bsum[i] = dir ? (bihb[n] + bhhb[n]) : (bihf[n] + bhhf[n]);
        }
    }
}

// ---------------------------------------------------------------------------
// k_gemm: xg_T[dir*tc+tt][n 512][b 4096] fp16 = (xh[tx] @ wh[dir]^T + bsum)^T
// 128x128 tile, K=256 in 2 halves, global_load_lds staging, XCD swizzle.
// ---------------------------------------------------------------------------
__global__ __launch_bounds__(256, 2) void k_gemm(
    const _Float16* __restrict__ xh, const _Float16* __restrict__ wh,
    const float* __restrict__ bsum, _Float16* __restrict__ xg,
    int t0, int tc)
{
    __shared__ __attribute__((aligned(16))) _Float16 lsA[128 * 128]; // 32KB
    __shared__ __attribute__((aligned(16))) _Float16 lsB[128 * 128]; // 32KB

    const int tid = threadIdx.x;
    const int nwg = gridDim.x;                 // 256*tc, %8==0
    const int f = blockIdx.x;
    const int q = nwg >> 3;
    const int wgid = (f & 7) * q + (f >> 3);   // bijective XCD swizzle
    const int ntile = wgid & 3;
    const int btile = (wgid >> 2) & 31;
    const int z = wgid >> 7;                   // 0..2*tc-1
    const int dir = (z >= tc) ? 1 : 0;
    const int tt = z - dir * tc;
    const int t = t0 + tt;
    const int tx = dir ? (NT - 1 - t) : t;

    const int lane = tid & 63;
    const int w = tid >> 6;
    const int wm = w >> 1, wn = w & 1;
    const int l15 = lane & 15, grp = lane >> 4;
    const int lr = lane >> 4, lc = lane & 15;

    const v4f vz = {0.f, 0.f, 0.f, 0.f};
    v4f acc[4][4];
#pragma unroll
    for (int i = 0; i < 4; ++i)
#pragma unroll
        for (int j = 0; j < 4; ++j) acc[i][j] = vz;

#pragma unroll
    for (int kh = 0; kh < 2; ++kh) {
#pragma unroll
        for (int j = 0; j < 8; ++j) {
            const int m = w * 32 + j * 4 + lr;
            const _Float16* ga = xh + ((size_t)tx * NB + btile * 128 + m) * NK
                                 + kh * 128 + lc * 8;
            gld16(ga, (char*)lsA + (w * 32 + j * 4) * 256);
            const _Float16* gb = wh + (size_t)(dir * NG + ntile * 128 + m) * NK
                                 + kh * 128 + lc * 8;
            gld16(gb, (char*)lsB + (w * 32 + j * 4) * 256);
        }
        __syncthreads();
#pragma unroll
        for (int ks = 0; ks < 4; ++ks) {
            v8h af[4], bfr[4];
#pragma unroll
            for (int mt = 0; mt < 4; ++mt) {
                const int row = wm * 64 + mt * 16 + l15;
                af[mt] = *(const v8h*)((const char*)lsA + row * 256
                          + (((ks * 4 + grp) ^ (row & 7)) << 4));
            }
#pragma unroll
            for (int nt = 0; nt < 4; ++nt) {
                const int row = wn * 64 + nt * 16 + l15;
                bfr[nt] = *(const v8h*)((const char*)lsB + row * 256
                          + (((ks * 4 + grp) ^ (row & 7)) << 4));
            }
#pragma unroll
            for (int mt = 0; mt < 4; ++mt)
#pragma unroll
                for (int nt = 0; nt < 4; ++nt)
                    acc[mt][nt] = __builtin_amdgcn_mfma_f32_16x16x32_f16(
                        af[mt], bfr[nt], acc[mt][nt], 0, 0, 0);
        }
        __syncthreads();
    }

    // epilogue: +bias, repack TRANSPOSED [n-local][b-local] via swizzled LDS
    float bias[4];
#pragma unroll
    for (int nt = 0; nt < 4; ++nt)
        bias[nt] = bsum[dir * NG + ntile * 128 + wn * 64 + nt * 16 + l15];
#pragma unroll
    for (int mt = 0; mt < 4; ++mt)
#pragma unroll
        for (int nt = 0; nt < 4; ++nt)
#pragma unroll
            for (int r = 0; r < 4; ++r) {
                const int col = wn * 64 + nt * 16 + l15;            // n-local
                const int row = wm * 64 + mt * 16 + (grp << 2) + r; // b-local
                const int byo = (col << 8) + ((row << 1) ^ ((col & 7) << 4));
                *(_Float16*)((char*)lsA + byo) = (_Float16)(acc[mt][nt][r] + bias[nt]);
            }
    __syncthreads();
    _Float16* obase = xg + ((size_t)(dir * tc + tt) * NG + ntile * 128) * NB
                      + btile * 128;
#pragma unroll
    for (int j = 0; j < 8; ++j) {
        const int idx = j * 256 + tid;
        const int n = idx >> 4, c = idx & 15;
        const v8h v = *(const v8h*)((const char*)lsA + (n << 8)
                        + ((c << 4) ^ ((n & 7) << 4)));
        *(v8h*)(obase + (size_t)n * NB + c * 8) = v;
    }
}

// ---------------------------------------------------------------------------
// k_scan: wave owns hcol slice w*16+l15, ALL 4 gates, 32 b-rows.
// Gate exchange is in-register; 1 barrier/step; xg tile async-staged dbuf.
// ---------------------------------------------------------------------------
__global__ __launch_bounds__(512) void k_scan(
    const _Float16* __restrict__ xg,     // [2tc][512][4096] fp16
    const _Float16* __restrict__ whh_h,  // [2][512][128] fp16
    _Float16* __restrict__ h_state,      // [2][NB][128]
    float* __restrict__ c_state,         // [2][NB][128]
    float* __restrict__ hsum,            // [2][NB][128]
    int tc, int first)
{
    __shared__ __attribute__((aligned(16))) _Float16 xbuf[2][512 * 32]; // 64KB
    __shared__ __attribute__((aligned(16))) _Float16 hbuf[2][32 * 128]; // 16KB

    const int tid   = threadIdx.x;
    const int btile = blockIdx.x;
    const int dir   = blockIdx.y;
    const int lane  = tid & 63;
    const int w     = tid >> 6;          // 0..7
    const int l15   = lane & 15;
    const int grp   = lane >> 4;
    const int rb    = btile * 32;
    const int hcol  = w * 16 + l15;

    const _Float16* whh = whh_h + (size_t)dir * NG * NH;

    v8h bw[4][4];
#pragma unroll
    for (int g = 0; g < 4; ++g)
#pragma unroll
        for (int ks = 0; ks < 4; ++ks)
            bw[g][ks] = *(const v8h*)(whh + (size_t)(g * 128 + hcol) * NH
                                      + ks * 32 + grp * 8);

    float c0[2][4], hs0[2][4];
    if (first) {
#pragma unroll
        for (int m = 0; m < 2; ++m)
#pragma unroll
            for (int r = 0; r < 4; ++r) { c0[m][r] = 0.f; hs0[m][r] = 0.f; }
    } else {
#pragma unroll
        for (int m = 0; m < 2; ++m)
#pragma unroll
            for (int r = 0; r < 4; ++r) {
                const size_t idx =
                    ((size_t)dir * NB + rb + m * 16 + grp * 4 + r) * NH + hcol;
                c0[m][r]  = c_state[idx];
                hs0[m][r] = hsum[idx];
            }
        for (int i = tid; i < 32 * 128; i += 512) {
            const int b = i >> 7, j = i & 127;
            const int byo = (b << 8) + ((j << 1) ^ ((b & 7) << 4));
            *(_Float16*)((char*)hbuf[0] + byo) =
                h_state[((size_t)dir * NB + rb + b) * NH + j];
        }
    }

    auto stage = [&](int tt, int buf) {
        const char* src = (const char*)xg
            + ((size_t)(dir * tc + tt) * NG) * (NB * 2);
#pragma unroll
        for (int jj = 0; jj < 4; ++jj) {
            const int nrow = w * 64 + jj * 16 + (lane >> 2);
            const char* g = src + (size_t)nrow * (NB * 2) + rb * 2 + (lane & 3) * 16;
            gld16(g, (char*)xbuf[buf] + (w * 64 + jj * 16) * 64);
        }
    };

    stage(0, 0);
    __syncthreads();   // drains stage vmcnt + hbuf init

    int cur = 0, hc = 0;
    for (int tt = 0; tt < tc; ++tt) {
        if (tt + 1 < tc) stage(tt + 1, cur ^ 1);   // async prefetch

        v4f acc[2][4];
#pragma unroll
        for (int m = 0; m < 2; ++m)
#pragma unroll
            for (int g = 0; g < 4; ++g) {
                const v4h xv = *(const v4h*)(xbuf[cur]
                    + (g * 128 + hcol) * 32 + m * 16 + grp * 4);
#pragma unroll
                for (int r = 0; r < 4; ++r) acc[m][g][r] = (float)xv[r];
            }

        if (!(first && tt == 0)) {
            v8h af[2][4];
#pragma unroll
            for (int m = 0; m < 2; ++m)
#pragma unroll
                for (int ks = 0; ks < 4; ++ks) {
                    const int row = m * 16 + l15;
                    af[m][ks] = *(const v8h*)((const char*)hbuf[hc] + (row << 8)
                                 + (((ks * 4 + grp) ^ (row & 7)) << 4));
                }
#pragma unroll
            for (int ks = 0; ks < 4; ++ks)
#pragma unroll
                for (int m = 0; m < 2; ++m)
#pragma unroll
                    for (int g = 0; g < 4; ++g)
                        acc[m][g] = __builtin_amdgcn_mfma_f32_16x16x32_f16(
                            af[m][ks], bw[g][ks], acc[m][g], 0, 0, 0);
        }

        // in-register gate math + c/h update (no exchange needed)
#pragma unroll
        for (int m = 0; m < 2; ++m)
#pragma unroll
            for (int r = 0; r < 4; ++r) {
                const float iv = fsig(acc[m][0][r]);
                const float fv = fsig(acc[m][1][r]);
                const float gv = ftanh(acc[m][2][r]);
                const float ov = fsig(acc[m][3][r]);
                const float c = fv * c0[m][r] + iv * gv;
                c0[m][r] = c;
                const float h = ov * ftanh(c);
                hs0[m][r] += h;
                const int b = m * 16 + grp * 4 + r;
                const int byo = (b << 8) + ((hcol << 1) ^ ((b & 7) << 4));
                *(_Float16*)((char*)hbuf[hc ^ 1] + byo) = (_Float16)h;
            }
        __syncthreads();   // drains prefetch vmcnt + h writes
        cur ^= 1; hc ^= 1;
    }

    // persist states
#pragma unroll
    for (int m = 0; m < 2; ++m)
#pragma unroll
        for (int r = 0; r < 4; ++r) {
            const size_t idx =
                ((size_t)dir * NB + rb + m * 16 + grp * 4 + r) * NH + hcol;
            c_state[idx] = c0[m][r];
            hsum[idx]    = hs0[m][r];
        }
    for (int i = tid; i < 32 * 128; i += 512) {
        const int b = i >> 7, j = i & 127;
        const int byo = (b << 8) + ((j << 1) ^ ((b & 7) << 4));
        h_state[((size_t)dir * NB + rb + b) * NH + j] =
            *(const _Float16*)((const char*)hbuf[hc] + byo);
    }
}

// ---------------------------------------------------------------------------
// k_head: pooled = hsum/T ; h1 = relu(pooled@fc1_w^T+b) ; out = h1@fc2_w^T+b
// ---------------------------------------------------------------------------
__global__ __launch_bounds__(128) void k_head(
    const float* __restrict__ hsum,
    const float* __restrict__ fc1w, const float* __restrict__ fc1b,
    const float* __restrict__ fc2w, const float* __restrict__ fc2b,
    float* __restrict__ out)
{
    __shared__ __attribute__((aligned(16))) float pooled[16][256];
    __shared__ __attribute__((aligned(16))) float h1s[16][128];
    __shared__ __attribute__((aligned(16))) char wbuf[65536];

    const int tid = threadIdx.x;
    const int rb  = blockIdx.x * 16;

    for (int i = tid; i < 16 * 256; i += 128) {
        const int r = i >> 8, c = i & 255;
        const float v = (c < 128)
            ? hsum[(size_t)(rb + r) * NH + c]
            : hsum[((size_t)NB + rb + r) * NH + (c - 128)];
        pooled[r][c] = v * (1.f / (float)NT);
    }
    for (int i = tid; i < 128 * 64; i += 128) {
        const int j = i >> 6, kq = i & 63;
        const float4 v = *(const float4*)(fc1w + (size_t)j * 256 + (kq << 2));
        v4h pv; pv[0] = (_Float16)v.x; pv[1] = (_Float16)v.y;
        pv[2] = (_Float16)v.z; pv[3] = (_Float16)v.w;
        const int byo = (j << 9) + ((kq << 3) ^ (((j >> 3) & 7) << 4));
        *(v4h*)(wbuf + byo) = pv;
    }
    __syncthreads();

    const int rgrp = tid >> 4;
    const int joct = tid & 15;
    const int r0 = rgrp * 2;
    const int j0 = joct * 8;

    float a1[2][8];
#pragma unroll
    for (int rr = 0; rr < 2; ++rr)
#pragma unroll
        for (int jo = 0; jo < 8; ++jo) a1[rr][jo] = 0.f;

    for (int kc = 0; kc < 32; ++kc) {
        const int k = kc << 3;
        float pv[2][8];
#pragma unroll
        for (int rr = 0; rr < 2; ++rr) {
            const float4 pa = *(const float4*)&pooled[r0 + rr][k];
            const float4 pb = *(const float4*)&pooled[r0 + rr][k + 4];
            pv[rr][0] = pa.x; pv[rr][1] = pa.y; pv[rr][2] = pa.z; pv[rr][3] = pa.w;
            pv[rr][4] = pb.x; pv[rr][5] = pb.y; pv[rr][6] = pb.z; pv[rr][7] = pb.w;
        }
#pragma unroll
        for (int jo = 0; jo < 8; ++jo) {
            const int j = j0 + jo;
            const int byo = (j << 9) + ((k << 1) ^ (((j >> 3) & 7) << 4));
            const v8h wv = *(const v8h*)(wbuf + byo);
#pragma unroll
            for (int i = 0; i < 8; ++i) {
                const float wf = (float)wv[i];
#pragma unroll
                for (int rr = 0; rr < 2; ++rr)
                    a1[rr][jo] += pv[rr][i] * wf;
            }
        }
    }
#pragma unroll
    for (int rr = 0; rr < 2; ++rr)
#pragma unroll
        for (int jo = 0; jo < 8; ++jo) {
            const int j = j0 + jo;
            const float v = a1[rr][jo] + fc1b[j];
            h1s[r0 + rr][j] = v > 0.f ? v : 0.f;
        }
    __syncthreads();

    for (int i = tid; i < 100 * 32; i += 128) {
        const int j = i >> 5, kq = i & 31;
        const float4 v = *(const float4*)(fc2w + (size_t)j * 128 + (kq << 2));
        const int byo = (j << 9) + ((kq << 4) ^ (((j >> 3) & 7) << 4));
        *(float4*)(wbuf + byo) = v;
    }
    __syncthreads();

    if (j0 < 100) {
        float a2[2][8];
#pragma unroll
        for (int rr = 0; rr < 2; ++rr)
#pragma unroll
            for (int jo = 0; jo < 8; ++jo) a2[rr][jo] = 0.f;

        for (int kc = 0; kc < 16; ++kc) {
            const int k = kc << 3;
            float hv[2][8];
#pragma unroll
            for (int rr = 0; rr < 2; ++rr) {
                const float4 ha = *(const float4*)&h1s[r0 + rr][k];
                const float4 hb = *(const float4*)&h1s[r0 + rr][k + 4];
                hv[rr][0] = ha.x; hv[rr][1] = ha.y; hv[rr][2] = ha.z; hv[rr][3] = ha.w;
                hv[rr][4] = hb.x; hv[rr][5] = hb.y; hv[rr][6] = hb.z; hv[rr][7] = hb.w;
            }
#pragma unroll
            for (int jo = 0; jo < 8; ++jo) {
                const int j = j0 + jo;
                if (j < 100) {
                    const int sw = ((j >> 3) & 7) << 4;
                    const float4 wa = *(const float4*)(wbuf + (j << 9) + ((k << 2) ^ sw));
                    const float4 wb = *(const float4*)(wbuf + (j << 9) + (((k + 4) << 2) ^ sw));
#pragma unroll
                    for (int rr = 0; rr < 2; ++rr) {
                        a2[rr][jo] += hv[rr][0] * wa.x + hv[rr][1] * wa.y
                                    + hv[rr][2] * wa.z + hv[rr][3] * wa.w
                                    + hv[rr][4] * wb.x + hv[rr][5] * wb.y
                                    + hv[rr][6] * wb.z + hv[rr][7] * wb.w;
                    }
                }
            }
        }
#pragma unroll
        for (int rr = 0; rr < 2; ++rr)
#pragma unroll
            for (int jo = 0; jo < 8; ++jo) {
                const int j = j0 + jo;
                if (j < 100)
                    out[(size_t)(rb + r0 + rr) * NCLS + j] = a2[rr][jo] + fc2b[j];
            }
    }
}

// ---------------------------------------------------------------------------
extern "C" void kernel_launch(void* const* d_in, const int* in_sizes, int n_in,
                              void* d_out, int out_size, void* d_ws, size_t ws_size,
                              hipStream_t stream)
{
    (void)in_sizes; (void)n_in; (void)out_size;
    const float* x    = (const float*)d_in[0];
    const float* wihf = (const float*)d_in[1];
    const float* whhf = (const float*)d_in[2];
    const float* bihf = (const float*)d_in[3];
    const float* bhhf = (const float*)d_in[4];
    const float* wihb = (const float*)d_in[5];
    const float* whhb = (const float*)d_in[6];
    const float* bihb = (const float*)d_in[7];
    const float* bhhb = (const float*)d_in[8];
    const float* fc1w = (const float*)d_in[9];
    const float* fc1b = (const float*)d_in[10];
    const float* fc2w = (const float*)d_in[11];
    const float* fc2b = (const float*)d_in[12];
    float* out = (float*)d_out;

    char* ws = (char*)d_ws;
    float*     c_state = (float*)ws;                                     // 4 MB
    float*     hs      = (float*)(ws + (size_t)4 * 1024 * 1024);         // 4 MB
    _Float16*  h_state = (_Float16*)(ws + (size_t)8 * 1024 * 1024);      // 2 MB
    size_t off = (size_t)10 * 1024 * 1024;
    _Float16*  xh    = (_Float16*)(ws + off); off += (size_t)NB * NT * NK * 2;  // 100.7 MB
    _Float16*  wh    = (_Float16*)(ws + off); off += (size_t)2 * NG * NK * 2;
    _Float16*  whh_h = (_Float16*)(ws + off); off += (size_t)2 * NG * NH * 2;
    float*     bsum  = (float*)(ws + off);    off += 1024 * 4;
    _Float16*  xgbuf = (_Float16*)(ws + off);

    const size_t per_t = (size_t)2 * NG * NB * 2;   // 8 MB per timestep (fp16)
    size_t avail = ws_size > off ? ws_size - off : 0;
    int tcmax = (int)(avail / per_t);
    if (tcmax < 1) tcmax = 1;
    int Tc = tcmax >= 16 ? 16 : tcmax;

    k_prep<<<dim3(NB + 161), dim3(256), 0, stream>>>(
        x, wihf, wihb, whhf, whhb, bihf, bhhf, bihb, bhhb, xh, wh, whh_h, bsum);

    int t0 = 0, first = 1;
    while (t0 < NT) {
        const int tc = (NT - t0 < Tc) ? (NT - t0) : Tc;
        k_gemm<<<dim3(256 * tc), dim3(256), 0, stream>>>(xh, wh, bsum, xgbuf, t0, tc);
        k_scan<<<dim3(128, 2), dim3(512), 0, stream>>>(
            xgbuf, whh_h, h_state, c_state, hs, tc, first);
        first = 0;
        t0 += tc;
    }
    k_head<<<dim3(256), dim3(128), 0, stream>>>(hs, fc1w, fc1b, fc2w, fc2b, out);
}

// Round 4
// 370.515 us; speedup vs baseline: 3.0684x; 1.3345x over previous
//
#include <hip/hip_runtime.h>
#include <stdint.h>

#define NB 4096
#define NT 48
#define NF 225
#define NH 128
#define NG 512   // 4*H
#define NK 256   // K padded 225->256
#define NCLS 100

typedef __attribute__((ext_vector_type(8))) _Float16 v8h;
typedef __attribute__((ext_vector_type(4))) _Float16 v4h;
typedef __attribute__((ext_vector_type(4))) float v4f;

__device__ __forceinline__ float fsig(float x) {
    return __builtin_amdgcn_rcpf(1.f + __expf(-x));
}
__device__ __forceinline__ float ftanh(float x) {
    return 2.f * __builtin_amdgcn_rcpf(1.f + __expf(-2.f * x)) - 1.f;
}

// global -> LDS direct copy, 16B per lane (dest = wave-uniform base + lane*16).
__device__ __forceinline__ void gld16(const void* g, void* l) {
    __builtin_amdgcn_global_load_lds(
        (const __attribute__((address_space(1))) void*)g,
        (__attribute__((address_space(3))) void*)l, 16, 0, 0);
}

// ---------------------------------------------------------------------------
// k_prep:
//  xh[t][b][256] fp16, zero-padded K, 16B chunks XOR-swizzled by (b&7)
//  wh[dir][512][256] fp16 LINEAR (read as per-lane register fragments)
//  whh_h[dir][512][128] fp16 linear
//  bsum[dir][512] = b_ih + b_hh (fp32)
// ---------------------------------------------------------------------------
__global__ __launch_bounds__(256) void k_prep(
    const float* __restrict__ x,
    const float* __restrict__ wihf, const float* __restrict__ wihb,
    const float* __restrict__ whhf, const float* __restrict__ whhb,
    const float* __restrict__ bihf, const float* __restrict__ bhhf,
    const float* __restrict__ bihb, const float* __restrict__ bhhb,
    _Float16* __restrict__ xh, _Float16* __restrict__ wh,
    _Float16* __restrict__ whh_h, float* __restrict__ bsum)
{
    __shared__ __attribute__((aligned(16))) _Float16 ls[NT * NF + 16];
    const int bid = blockIdx.x;
    const int tid = threadIdx.x;

    if (bid < NB) {
        const float* src = x + (size_t)bid * (NT * NF);   // 43200B contiguous
        for (int i = tid; i < (NT * NF) / 4; i += 256) {  // 2700 float4
            const float4 v = ((const float4*)src)[i];
            v4h hv; hv[0] = (_Float16)v.x; hv[1] = (_Float16)v.y;
            hv[2] = (_Float16)v.z; hv[3] = (_Float16)v.w;
            *(v4h*)(ls + i * 4) = hv;
        }
        __syncthreads();
        const int key = bid & 7;
        for (int task = tid; task < NT * 32; task += 256) {
            const int t = task >> 5, c = task & 31;
            v8h hv;
#pragma unroll
            for (int e = 0; e < 8; ++e) {
                const int k = c * 8 + e;
                hv[e] = (k < NF) ? ls[t * NF + k] : (_Float16)0.f;
            }
            *(v8h*)(xh + ((size_t)t * NB + bid) * NK + ((c ^ key) << 3)) = hv;
        }
    } else if (bid < NB + 128) {
        const int r = (bid - NB) * 8 + (tid >> 5);   // 0..1023
        const int c = tid & 31;
        const int dir = r >> 9, n = r & 511;
        const float* src = (dir ? wihb : wihf) + (size_t)n * NF + c * 8;
        v8h hv;
#pragma unroll
        for (int i = 0; i < 8; ++i) {
            const int k = c * 8 + i;
            hv[i] = (k < NF) ? (_Float16)src[i] : (_Float16)0.f;
        }
        *(v8h*)(wh + (size_t)r * NK + (c << 3)) = hv;   // LINEAR
    } else if (bid < NB + 160) {
        const int base = (bid - NB - 128) * 4096 + tid;   // whh: 131072 elems
#pragma unroll
        for (int s = 0; s < 16; ++s) {
            const int i = base + s * 256;
            whh_h[i] = (_Float16)((i < 65536) ? whhf[i] : whhb[i - 65536]);
        }
    } else {
        for (int i = tid; i < 1024; i += 256) {
            const int dir = i >> 9, n = i & 511;
            bsum[i] = dir ? (bihb[n] + bhhb[n]) : (bihf[n] + bhhf[n]);
        }
    }
}

// ---------------------------------------------------------------------------
// k_fused: input GEMM + LSTM recurrence + hsum accumulation, one dispatch.
// Block = 32 batch rows x one direction; 8 waves; wave owns hcol slice
// (w*16+l15) across ALL 4 gates; B_ih and whh fragments persistent in VGPRs.
// Per step: prefetch next x-tile (16KB contiguous gld16) -> x-MFMA (K=256)
// + h-MFMA (K=128) -> in-register gates -> h to LDS dbuf -> 1 barrier.
// ---------------------------------------------------------------------------
__global__ __launch_bounds__(512, 2) void k_fused(
    const _Float16* __restrict__ xh,     // [48][4096][256] pre-swizzled (b&7)
    const _Float16* __restrict__ wh,     // [2][512][256] linear
    const _Float16* __restrict__ whh_h,  // [2][512][128] linear
    const float* __restrict__ bsum,      // [2][512]
    float* __restrict__ hsum)            // [2][4096][128]
{
    __shared__ __attribute__((aligned(16))) _Float16 xb[2][32 * 256]; // 2x16KB
    __shared__ __attribute__((aligned(16))) _Float16 hb[2][32 * 128]; // 2x8KB

    const int tid  = threadIdx.x;
    const int btile = blockIdx.x;        // 0..127
    const int dir   = blockIdx.y;
    const int rb    = btile * 32;
    const int lane  = tid & 63;
    const int w     = tid >> 6;          // 0..7
    const int l15   = lane & 15;
    const int grp   = lane >> 4;
    const int hcol  = w * 16 + l15;      // 0..127

    // persistent weight fragments (one-time per-lane gathers, L2/L3-hot)
    v8h bx[4][8];   // w_ih: gate g, k-slice ks (K=256)
#pragma unroll
    for (int g = 0; g < 4; ++g)
#pragma unroll
        for (int ks = 0; ks < 8; ++ks)
            bx[g][ks] = *(const v8h*)(wh +
                (size_t)(dir * NG + g * NH + hcol) * NK + ks * 32 + grp * 8);
    v8h bh[4][4];   // whh: gate g, k-slice ks (K=128)
#pragma unroll
    for (int g = 0; g < 4; ++g)
#pragma unroll
        for (int ks = 0; ks < 4; ++ks)
            bh[g][ks] = *(const v8h*)(whh_h +
                (size_t)(dir * NG + g * NH + hcol) * NH + ks * 32 + grp * 8);
    float bias[4];
#pragma unroll
    for (int g = 0; g < 4; ++g)
        bias[g] = bsum[dir * NG + g * NH + hcol];

    float c0[2][4], hs0[2][4];
#pragma unroll
    for (int m = 0; m < 2; ++m)
#pragma unroll
        for (int r = 0; r < 4; ++r) { c0[m][r] = 0.f; hs0[m][r] = 0.f; }

    auto stage = [&](int tx, int buf) {
        const char* src = (const char*)(xh + ((size_t)tx * NB + rb) * NK);
#pragma unroll
        for (int c = 0; c < 2; ++c) {
            const int seg = w * 2 + c;            // 16 x 1KB segments
            gld16(src + (seg << 10) + lane * 16, (char*)xb[buf] + (seg << 10));
        }
    };

    stage(dir ? (NT - 1) : 0, 0);
    __syncthreads();

    int cur = 0, hc = 0;
#pragma unroll 1
    for (int t = 0; t < NT; ++t) {
        if (t + 1 < NT)
            stage(dir ? (NT - 2 - t) : (t + 1), cur ^ 1);   // async prefetch

        // x-part A fragments from LDS (swizzle matches prep's (b&7) XOR)
        v8h af[2][8];
#pragma unroll
        for (int m = 0; m < 2; ++m) {
            const int row = m * 16 + l15;
#pragma unroll
            for (int ks = 0; ks < 8; ++ks)
                af[m][ks] = *(const v8h*)((const char*)xb[cur] + row * 512
                             + (((ks * 4 + grp) ^ (row & 7)) << 4));
        }

        v4f acc[2][4];
#pragma unroll
        for (int m = 0; m < 2; ++m)
#pragma unroll
            for (int g = 0; g < 4; ++g)
                acc[m][g] = (v4f){bias[g], bias[g], bias[g], bias[g]};

#pragma unroll
        for (int ks = 0; ks < 8; ++ks)
#pragma unroll
            for (int m = 0; m < 2; ++m)
#pragma unroll
                for (int g = 0; g < 4; ++g)
                    acc[m][g] = __builtin_amdgcn_mfma_f32_16x16x32_f16(
                        af[m][ks], bx[g][ks], acc[m][g], 0, 0, 0);

        if (t > 0) {
            v8h ah[2][4];
#pragma unroll
            for (int m = 0; m < 2; ++m) {
                const int row = m * 16 + l15;
#pragma unroll
                for (int ks = 0; ks < 4; ++ks)
                    ah[m][ks] = *(const v8h*)((const char*)hb[hc] + row * 256
                                 + (((ks * 4 + grp) ^ (row & 7)) << 4));
            }
#pragma unroll
            for (int ks = 0; ks < 4; ++ks)
#pragma unroll
                for (int m = 0; m < 2; ++m)
#pragma unroll
                    for (int g = 0; g < 4; ++g)
                        acc[m][g] = __builtin_amdgcn_mfma_f32_16x16x32_f16(
                            ah[m][ks], bh[g][ks], acc[m][g], 0, 0, 0);
        }

        // gates + state update, all in-register; h -> LDS dbuf (swizzled)
#pragma unroll
        for (int m = 0; m < 2; ++m)
#pragma unroll
            for (int r = 0; r < 4; ++r) {
                const float iv = fsig(acc[m][0][r]);
                const float fv = fsig(acc[m][1][r]);
                const float gv = ftanh(acc[m][2][r]);
                const float ov = fsig(acc[m][3][r]);
                const float c = fv * c0[m][r] + iv * gv;
                c0[m][r] = c;
                const float h = ov * ftanh(c);
                hs0[m][r] += h;
                const int b = m * 16 + grp * 4 + r;
                const int byo = (b << 8) + ((hcol << 1) ^ ((b & 7) << 4));
                *(_Float16*)((char*)hb[hc ^ 1] + byo) = (_Float16)h;
            }
        __syncthreads();   // h visible + prefetch drained (vmcnt at barrier)
        cur ^= 1; hc ^= 1;
    }

#pragma unroll
    for (int m = 0; m < 2; ++m)
#pragma unroll
        for (int r = 0; r < 4; ++r)
            hsum[((size_t)dir * NB + rb + m * 16 + grp * 4 + r) * NH + hcol] =
                hs0[m][r];
}

// ---------------------------------------------------------------------------
// k_head: pooled = hsum/T ; h1 = relu(pooled@fc1_w^T+b) ; out = h1@fc2_w^T+b
// ---------------------------------------------------------------------------
__global__ __launch_bounds__(128) void k_head(
    const float* __restrict__ hsum,
    const float* __restrict__ fc1w, const float* __restrict__ fc1b,
    const float* __restrict__ fc2w, const float* __restrict__ fc2b,
    float* __restrict__ out)
{
    __shared__ __attribute__((aligned(16))) float pooled[16][256];
    __shared__ __attribute__((aligned(16))) float h1s[16][128];
    __shared__ __attribute__((aligned(16))) char wbuf[65536];

    const int tid = threadIdx.x;
    const int rb  = blockIdx.x * 16;

    for (int i = tid; i < 16 * 256; i += 128) {
        const int r = i >> 8, c = i & 255;
        const float v = (c < 128)
            ? hsum[(size_t)(rb + r) * NH + c]
            : hsum[((size_t)NB + rb + r) * NH + (c - 128)];
        pooled[r][c] = v * (1.f / (float)NT);
    }
    for (int i = tid; i < 128 * 64; i += 128) {
        const int j = i >> 6, kq = i & 63;
        const float4 v = *(const float4*)(fc1w + (size_t)j * 256 + (kq << 2));
        v4h pv; pv[0] = (_Float16)v.x; pv[1] = (_Float16)v.y;
        pv[2] = (_Float16)v.z; pv[3] = (_Float16)v.w;
        const int byo = (j << 9) + ((kq << 3) ^ (((j >> 3) & 7) << 4));
        *(v4h*)(wbuf + byo) = pv;
    }
    __syncthreads();

    const int rgrp = tid >> 4;
    const int joct = tid & 15;
    const int r0 = rgrp * 2;
    const int j0 = joct * 8;

    float a1[2][8];
#pragma unroll
    for (int rr = 0; rr < 2; ++rr)
#pragma unroll
        for (int jo = 0; jo < 8; ++jo) a1[rr][jo] = 0.f;

    for (int kc = 0; kc < 32; ++kc) {
        const int k = kc << 3;
        float pv[2][8];
#pragma unroll
        for (int rr = 0; rr < 2; ++rr) {
            const float4 pa = *(const float4*)&pooled[r0 + rr][k];
            const float4 pb = *(const float4*)&pooled[r0 + rr][k + 4];
            pv[rr][0] = pa.x; pv[rr][1] = pa.y; pv[rr][2] = pa.z; pv[rr][3] = pa.w;
            pv[rr][4] = pb.x; pv[rr][5] = pb.y; pv[rr][6] = pb.z; pv[rr][7] = pb.w;
        }
#pragma unroll
        for (int jo = 0; jo < 8; ++jo) {
            const int j = j0 + jo;
            const int byo = (j << 9) + ((k << 1) ^ (((j >> 3) & 7) << 4));
            const v8h wv = *(const v8h*)(wbuf + byo);
#pragma unroll
            for (int i = 0; i < 8; ++i) {
                const float wf = (float)wv[i];
#pragma unroll
                for (int rr = 0; rr < 2; ++rr)
                    a1[rr][jo] += pv[rr][i] * wf;
            }
        }
    }
#pragma unroll
    for (int rr = 0; rr < 2; ++rr)
#pragma unroll
        for (int jo = 0; jo < 8; ++jo) {
            const int j = j0 + jo;
            const float v = a1[rr][jo] + fc1b[j];
            h1s[r0 + rr][j] = v > 0.f ? v : 0.f;
        }
    __syncthreads();

    for (int i = tid; i < 100 * 32; i += 128) {
        const int j = i >> 5, kq = i & 31;
        const float4 v = *(const float4*)(fc2w + (size_t)j * 128 + (kq << 2));
        const int byo = (j << 9) + ((kq << 4) ^ (((j >> 3) & 7) << 4));
        *(float4*)(wbuf + byo) = v;
    }
    __syncthreads();

    if (j0 < 100) {
        float a2[2][8];
#pragma unroll
        for (int rr = 0; rr < 2; ++rr)
#pragma unroll
            for (int jo = 0; jo < 8; ++jo) a2[rr][jo] = 0.f;

        for (int kc = 0; kc < 16; ++kc) {
            const int k = kc << 3;
            float hv[2][8];
#pragma unroll
            for (int rr = 0; rr < 2; ++rr) {
                const float4 ha = *(const float4*)&h1s[r0 + rr][k];
                const float4 hbv = *(const float4*)&h1s[r0 + rr][k + 4];
                hv[rr][0] = ha.x; hv[rr][1] = ha.y; hv[rr][2] = ha.z; hv[rr][3] = ha.w;
                hv[rr][4] = hbv.x; hv[rr][5] = hbv.y; hv[rr][6] = hbv.z; hv[rr][7] = hbv.w;
            }
#pragma unroll
            for (int jo = 0; jo < 8; ++jo) {
                const int j = j0 + jo;
                if (j < 100) {
                    const int sw = ((j >> 3) & 7) << 4;
                    const float4 wa = *(const float4*)(wbuf + (j << 9) + ((k << 2) ^ sw));
                    const float4 wb = *(const float4*)(wbuf + (j << 9) + (((k + 4) << 2) ^ sw));
#pragma unroll
                    for (int rr = 0; rr < 2; ++rr) {
                        a2[rr][jo] += hv[rr][0] * wa.x + hv[rr][1] * wa.y
                                    + hv[rr][2] * wa.z + hv[rr][3] * wa.w
                                    + hv[rr][4] * wb.x + hv[rr][5] * wb.y
                                    + hv[rr][6] * wb.z + hv[rr][7] * wb.w;
                    }
                }
            }
        }
#pragma unroll
        for (int rr = 0; rr < 2; ++rr)
#pragma unroll
            for (int jo = 0; jo < 8; ++jo) {
                const int j = j0 + jo;
                if (j < 100)
                    out[(size_t)(rb + r0 + rr) * NCLS + j] = a2[rr][jo] + fc2b[j];
            }
    }
}

// ---------------------------------------------------------------------------
extern "C" void kernel_launch(void* const* d_in, const int* in_sizes, int n_in,
                              void* d_out, int out_size, void* d_ws, size_t ws_size,
                              hipStream_t stream)
{
    (void)in_sizes; (void)n_in; (void)out_size; (void)ws_size;
    const float* x    = (const float*)d_in[0];
    const float* wihf = (const float*)d_in[1];
    const float* whhf = (const float*)d_in[2];
    const float* bihf = (const float*)d_in[3];
    const float* bhhf = (const float*)d_in[4];
    const float* wihb = (const float*)d_in[5];
    const float* whhb = (const float*)d_in[6];
    const float* bihb = (const float*)d_in[7];
    const float* bhhb = (const float*)d_in[8];
    const float* fc1w = (const float*)d_in[9];
    const float* fc1b = (const float*)d_in[10];
    const float* fc2w = (const float*)d_in[11];
    const float* fc2b = (const float*)d_in[12];
    float* out = (float*)d_out;

    char* ws = (char*)d_ws;
    float*     hs    = (float*)ws;                                    // 4 MB
    size_t off = (size_t)4 * 1024 * 1024;
    _Float16*  xh    = (_Float16*)(ws + off); off += (size_t)NB * NT * NK * 2; // 100.7 MB
    _Float16*  wh    = (_Float16*)(ws + off); off += (size_t)2 * NG * NK * 2;
    _Float16*  whh_h = (_Float16*)(ws + off); off += (size_t)2 * NG * NH * 2;
    float*     bsum  = (float*)(ws + off);    off += 1024 * 4;

    k_prep<<<dim3(NB + 161), dim3(256), 0, stream>>>(
        x, wihf, wihb, whhf, whhb, bihf, bhhf, bihb, bhhb, xh, wh, whh_h, bsum);
    k_fused<<<dim3(128, 2), dim3(512), 0, stream>>>(xh, wh, whh_h, bsum, hs);
    k_head<<<dim3(256), dim3(128), 0, stream>>>(hs, fc1w, fc1b, fc2w, fc2b, out);
}

// Round 5
// 280.913 us; speedup vs baseline: 4.0472x; 1.3190x over previous
//
#include <hip/hip_runtime.h>
#include <stdint.h>

#define NB 4096
#define NT 48
#define NF 225
#define NH 128
#define NG 512   // 4*H
#define NK 256   // K padded 225->256
#define NCLS 100

typedef __attribute__((ext_vector_type(8))) _Float16 v8h;
typedef __attribute__((ext_vector_type(4))) _Float16 v4h;
typedef __attribute__((ext_vector_type(4))) float v4f;

__device__ __forceinline__ float fsig(float x) {
    return __builtin_amdgcn_rcpf(1.f + __expf(-x));
}
__device__ __forceinline__ float ftanh(float x) {
    return 2.f * __builtin_amdgcn_rcpf(1.f + __expf(-2.f * x)) - 1.f;
}
// keep loop-invariant LDS-B loads from being hoisted (register budget!)
__device__ __forceinline__ int opq(int x) { asm volatile("" : "+v"(x)); return x; }

// global -> LDS direct copy, 16B per lane (dest = wave-uniform base + lane*16).
__device__ __forceinline__ void gld16(const void* g, void* l) {
    __builtin_amdgcn_global_load_lds(
        (const __attribute__((address_space(1))) void*)g,
        (__attribute__((address_space(3))) void*)l, 16, 0, 0);
}

// ---------------------------------------------------------------------------
// k_prep:
//  xh[t][b][256]   fp16, zero-padded K, 16B chunks XOR-swizzled by (b&7)
//  wh[dir][512][256]   fp16 LINEAR (register-fragment gathers, gates i,f,g)
//  whh_h[dir][512][128] fp16 linear
//  wh3[dir][128][256]  gate-o w_ih rows, chunk-swizzled by (col&7)  (LDS copy)
//  whh3[dir][128][128] gate-o w_hh rows, chunk-swizzled by (col&7)
//  bsum[dir][512] = b_ih + b_hh (fp32)
// ---------------------------------------------------------------------------
__global__ __launch_bounds__(256) void k_prep(
    const float* __restrict__ x,
    const float* __restrict__ wihf, const float* __restrict__ wihb,
    const float* __restrict__ whhf, const float* __restrict__ whhb,
    const float* __restrict__ bihf, const float* __restrict__ bhhf,
    const float* __restrict__ bihb, const float* __restrict__ bhhb,
    _Float16* __restrict__ xh, _Float16* __restrict__ wh,
    _Float16* __restrict__ whh_h, _Float16* __restrict__ wh3,
    _Float16* __restrict__ whh3, float* __restrict__ bsum)
{
    __shared__ __attribute__((aligned(16))) _Float16 ls[NT * NF + 16];
    const int bid = blockIdx.x;
    const int tid = threadIdx.x;

    if (bid < NB) {
        const float* src = x + (size_t)bid * (NT * NF);   // 43200B contiguous
        for (int i = tid; i < (NT * NF) / 4; i += 256) {
            const float4 v = ((const float4*)src)[i];
            v4h hv; hv[0] = (_Float16)v.x; hv[1] = (_Float16)v.y;
            hv[2] = (_Float16)v.z; hv[3] = (_Float16)v.w;
            *(v4h*)(ls + i * 4) = hv;
        }
        __syncthreads();
        const int key = bid & 7;
        for (int task = tid; task < NT * 32; task += 256) {
            const int t = task >> 5, c = task & 31;
            v8h hv;
#pragma unroll
            for (int e = 0; e < 8; ++e) {
                const int k = c * 8 + e;
                hv[e] = (k < NF) ? ls[t * NF + k] : (_Float16)0.f;
            }
            *(v8h*)(xh + ((size_t)t * NB + bid) * NK + ((c ^ key) << 3)) = hv;
        }
    } else if (bid < NB + 128) {
        const int r = (bid - NB) * 8 + (tid >> 5);   // 0..1023
        const int c = tid & 31;
        const int dir = r >> 9, n = r & 511;
        const float* src = (dir ? wihb : wihf) + (size_t)n * NF + c * 8;
        v8h hv;
#pragma unroll
        for (int i = 0; i < 8; ++i) {
            const int k = c * 8 + i;
            hv[i] = (k < NF) ? (_Float16)src[i] : (_Float16)0.f;
        }
        *(v8h*)(wh + (size_t)r * NK + (c << 3)) = hv;   // LINEAR
    } else if (bid < NB + 160) {
        const int base = (bid - NB - 128) * 4096 + tid;   // whh: 131072 elems
#pragma unroll
        for (int s = 0; s < 16; ++s) {
            const int i = base + s * 256;
            whh_h[i] = (_Float16)((i < 65536) ? whhf[i] : whhb[i - 65536]);
        }
    } else if (bid < NB + 164) {
        // wh3: gate-o (rows 384..511) of w_ih, chunk-swizzled by (col&7)
        for (int s = 0; s < 8; ++s) {
            const int task = (bid - NB - 160) * 2048 + s * 256 + tid; // 0..8191
            const int dir = task >> 12;
            const int rem = task & 4095;
            const int col = rem >> 5, c = rem & 31;
            const float* src = (dir ? wihb : wihf) + (size_t)(384 + col) * NF + c * 8;
            v8h hv;
#pragma unroll
            for (int e = 0; e < 8; ++e) {
                const int k = c * 8 + e;
                hv[e] = (k < NF) ? (_Float16)src[e] : (_Float16)0.f;
            }
            *(v8h*)(wh3 + ((size_t)dir * 128 + col) * NK + ((c ^ (col & 7)) << 3)) = hv;
        }
    } else if (bid < NB + 166) {
        // whh3: gate-o (rows 384..511) of w_hh, chunk-swizzled by (col&7)
        for (int s = 0; s < 8; ++s) {
            const int task = (bid - NB - 164) * 2048 + s * 256 + tid; // 0..4095
            const int dir = task >> 11;
            const int rem = task & 2047;
            const int col = rem >> 4, c = rem & 15;
            const float* src = (dir ? whhb : whhf) + (size_t)(384 + col) * NH + c * 8;
            v8h hv;
#pragma unroll
            for (int e = 0; e < 8; ++e) hv[e] = (_Float16)src[e];
            *(v8h*)(whh3 + ((size_t)dir * 128 + col) * NH + ((c ^ (col & 7)) << 3)) = hv;
        }
    } else {
        for (int i = tid; i < 1024; i += 256) {
            const int dir = i >> 9, n = i & 511;
            bsum[i] = dir ? (bihb[n] + bhhb[n]) : (bihf[n] + bhhf[n]);
        }
    }
}

// ---------------------------------------------------------------------------
// k_fused: input GEMM + LSTM recurrence + hsum, one dispatch.
// Block = 32 b-rows x dir; 8 waves; wave owns hcol = w*16+l15, all 4 gates.
// Gates i,f,g: B-fragments persistent in VGPRs (144 VGPR).
// Gate o: B streamed per-step from LDS (bxo 64KB + bho 32KB, preloaded once).
// ---------------------------------------------------------------------------
__global__ __launch_bounds__(512, 2) void k_fused(
    const _Float16* __restrict__ xh,     // [48][4096][256] swizzled (b&7)
    const _Float16* __restrict__ wh,     // [2][512][256] linear
    const _Float16* __restrict__ whh_h,  // [2][512][128] linear
    const _Float16* __restrict__ wh3,    // [2][128][256] swizzled (col&7)
    const _Float16* __restrict__ whh3,   // [2][128][128] swizzled (col&7)
    const float* __restrict__ bsum,      // [2][512]
    float* __restrict__ hsum)            // [2][4096][128]
{
    __shared__ __attribute__((aligned(16))) _Float16 xb[2][32 * 256]; // 32KB
    __shared__ __attribute__((aligned(16))) _Float16 hb[2][32 * 128]; // 16KB
    __shared__ __attribute__((aligned(16))) _Float16 bxo[128 * 256];  // 64KB
    __shared__ __attribute__((aligned(16))) _Float16 bho[128 * 128];  // 32KB

    const int tid   = threadIdx.x;
    const int btile = blockIdx.x;        // 0..127
    const int dir   = blockIdx.y;
    const int rb    = btile * 32;
    const int lane  = tid & 63;
    const int w     = tid >> 6;          // 0..7
    const int l15   = lane & 15;
    const int grp   = lane >> 4;
    const int hcol  = w * 16 + l15;      // 0..127
    const int swz   = hcol & 7;

    // one-time LDS preload of gate-o weights (pre-swizzled source, DMA)
#pragma unroll
    for (int j = 0; j < 12; ++j) {
        const int seg = w + j * 8;       // 0..95
        if (seg < 64)
            gld16((const char*)wh3 + (size_t)dir * 65536 + (seg << 10) + lane * 16,
                  (char*)bxo + (seg << 10));
        else
            gld16((const char*)whh3 + (size_t)dir * 32768 + ((seg - 64) << 10) + lane * 16,
                  (char*)bho + ((seg - 64) << 10));
    }

    // persistent register fragments: gates 0..2 (i,f,g)
    v8h bx[3][8];
#pragma unroll
    for (int g = 0; g < 3; ++g)
#pragma unroll
        for (int ks = 0; ks < 8; ++ks)
            bx[g][ks] = *(const v8h*)(wh +
                (size_t)(dir * NG + g * NH + hcol) * NK + ks * 32 + grp * 8);
    v8h bh[3][4];
#pragma unroll
    for (int g = 0; g < 3; ++g)
#pragma unroll
        for (int ks = 0; ks < 4; ++ks)
            bh[g][ks] = *(const v8h*)(whh_h +
                (size_t)(dir * NG + g * NH + hcol) * NH + ks * 32 + grp * 8);
    float bias[4];
#pragma unroll
    for (int g = 0; g < 4; ++g)
        bias[g] = bsum[dir * NG + g * NH + hcol];

    float c0[2][4], hs0[2][4];
#pragma unroll
    for (int m = 0; m < 2; ++m)
#pragma unroll
        for (int r = 0; r < 4; ++r) { c0[m][r] = 0.f; hs0[m][r] = 0.f; }

    auto stage = [&](int tx, int buf) {
        const char* src = (const char*)(xh + ((size_t)tx * NB + rb) * NK);
#pragma unroll
        for (int c = 0; c < 2; ++c) {
            const int seg = w * 2 + c;            // 16 x 1KB segments
            gld16(src + (seg << 10) + lane * 16, (char*)xb[buf] + (seg << 10));
        }
    };

    stage(dir ? (NT - 1) : 0, 0);
    __syncthreads();   // preloads + stage drained

    int cur = 0, hc = 0;
#pragma unroll 1
    for (int t = 0; t < NT; ++t) {
        if (t + 1 < NT)
            stage(dir ? (NT - 2 - t) : (t + 1), cur ^ 1);   // async prefetch

        v4f acc[2][4];
#pragma unroll
        for (int m = 0; m < 2; ++m)
#pragma unroll
            for (int g = 0; g < 4; ++g)
                acc[m][g] = (v4f){bias[g], bias[g], bias[g], bias[g]};

        // x-part: K=256 in 8 slices; gates 0-2 reg-B, gate 3 LDS-B
#pragma unroll
        for (int ks = 0; ks < 8; ++ks) {
            const int ch = ((ks * 4 + grp) ^ swz) << 4;
            v8h af0 = *(const v8h*)((const char*)xb[cur] + (l15 << 9)
                        + ((((ks * 4 + grp) ^ (l15 & 7))) << 4));
            v8h af1 = *(const v8h*)((const char*)xb[cur] + ((16 + l15) << 9)
                        + ((((ks * 4 + grp) ^ (l15 & 7))) << 4));
            v8h bo = *(const v8h*)((const char*)bxo + opq((hcol << 9) + ch));
            acc[0][0] = __builtin_amdgcn_mfma_f32_16x16x32_f16(af0, bx[0][ks], acc[0][0], 0, 0, 0);
            acc[1][0] = __builtin_amdgcn_mfma_f32_16x16x32_f16(af1, bx[0][ks], acc[1][0], 0, 0, 0);
            acc[0][1] = __builtin_amdgcn_mfma_f32_16x16x32_f16(af0, bx[1][ks], acc[0][1], 0, 0, 0);
            acc[1][1] = __builtin_amdgcn_mfma_f32_16x16x32_f16(af1, bx[1][ks], acc[1][1], 0, 0, 0);
            acc[0][2] = __builtin_amdgcn_mfma_f32_16x16x32_f16(af0, bx[2][ks], acc[0][2], 0, 0, 0);
            acc[1][2] = __builtin_amdgcn_mfma_f32_16x16x32_f16(af1, bx[2][ks], acc[1][2], 0, 0, 0);
            acc[0][3] = __builtin_amdgcn_mfma_f32_16x16x32_f16(af0, bo, acc[0][3], 0, 0, 0);
            acc[1][3] = __builtin_amdgcn_mfma_f32_16x16x32_f16(af1, bo, acc[1][3], 0, 0, 0);
        }

        // h-part: K=128 in 4 slices
        if (t > 0) {
#pragma unroll
            for (int ks = 0; ks < 4; ++ks) {
                const int ch = ((ks * 4 + grp) ^ swz) << 4;
                v8h ah0 = *(const v8h*)((const char*)hb[hc] + (l15 << 8)
                            + ((((ks * 4 + grp) ^ (l15 & 7))) << 4));
                v8h ah1 = *(const v8h*)((const char*)hb[hc] + ((16 + l15) << 8)
                            + ((((ks * 4 + grp) ^ (l15 & 7))) << 4));
                v8h bo2 = *(const v8h*)((const char*)bho + opq((hcol << 8) + ch));
                acc[0][0] = __builtin_amdgcn_mfma_f32_16x16x32_f16(ah0, bh[0][ks], acc[0][0], 0, 0, 0);
                acc[1][0] = __builtin_amdgcn_mfma_f32_16x16x32_f16(ah1, bh[0][ks], acc[1][0], 0, 0, 0);
                acc[0][1] = __builtin_amdgcn_mfma_f32_16x16x32_f16(ah0, bh[1][ks], acc[0][1], 0, 0, 0);
                acc[1][1] = __builtin_amdgcn_mfma_f32_16x16x32_f16(ah1, bh[1][ks], acc[1][1], 0, 0, 0);
                acc[0][2] = __builtin_amdgcn_mfma_f32_16x16x32_f16(ah0, bh[2][ks], acc[0][2], 0, 0, 0);
                acc[1][2] = __builtin_amdgcn_mfma_f32_16x16x32_f16(ah1, bh[2][ks], acc[1][2], 0, 0, 0);
                acc[0][3] = __builtin_amdgcn_mfma_f32_16x16x32_f16(ah0, bo2, acc[0][3], 0, 0, 0);
                acc[1][3] = __builtin_amdgcn_mfma_f32_16x16x32_f16(ah1, bo2, acc[1][3], 0, 0, 0);
            }
        }

        // gates + state update in-register; h -> LDS dbuf (swizzled)
#pragma unroll
        for (int m = 0; m < 2; ++m)
#pragma unroll
            for (int r = 0; r < 4; ++r) {
                const float iv = fsig(acc[m][0][r]);
                const float fv = fsig(acc[m][1][r]);
                const float gv = ftanh(acc[m][2][r]);
                const float ov = fsig(acc[m][3][r]);
                const float c = fv * c0[m][r] + iv * gv;
                c0[m][r] = c;
                const float h = ov * ftanh(c);
                hs0[m][r] += h;
                const int b = m * 16 + grp * 4 + r;
                const int byo = (b << 8) + ((hcol << 1) ^ ((b & 7) << 4));
                *(_Float16*)((char*)hb[hc ^ 1] + byo) = (_Float16)h;
            }
        __syncthreads();   // h visible + prefetch DMA drained
        cur ^= 1; hc ^= 1;
    }

#pragma unroll
    for (int m = 0; m < 2; ++m)
#pragma unroll
        for (int r = 0; r < 4; ++r)
            hsum[((size_t)dir * NB + rb + m * 16 + grp * 4 + r) * NH + hcol] =
                hs0[m][r];
}

// ---------------------------------------------------------------------------
// k_head: pooled = hsum/T ; h1 = relu(pooled@fc1_w^T+b) ; out = h1@fc2_w^T+b
// ---------------------------------------------------------------------------
__global__ __launch_bounds__(128) void k_head(
    const float* __restrict__ hsum,
    const float* __restrict__ fc1w, const float* __restrict__ fc1b,
    const float* __restrict__ fc2w, const float* __restrict__ fc2b,
    float* __restrict__ out)
{
    __shared__ __attribute__((aligned(16))) float pooled[16][256];
    __shared__ __attribute__((aligned(16))) float h1s[16][128];
    __shared__ __attribute__((aligned(16))) char wbuf[65536];

    const int tid = threadIdx.x;
    const int rb  = blockIdx.x * 16;

    for (int i = tid; i < 16 * 256; i += 128) {
        const int r = i >> 8, c = i & 255;
        const float v = (c < 128)
            ? hsum[(size_t)(rb + r) * NH + c]
            : hsum[((size_t)NB + rb + r) * NH + (c - 128)];
        pooled[r][c] = v * (1.f / (float)NT);
    }
    for (int i = tid; i < 128 * 64; i += 128) {
        const int j = i >> 6, kq = i & 63;
        const float4 v = *(const float4*)(fc1w + (size_t)j * 256 + (kq << 2));
        v4h pv; pv[0] = (_Float16)v.x; pv[1] = (_Float16)v.y;
        pv[2] = (_Float16)v.z; pv[3] = (_Float16)v.w;
        const int byo = (j << 9) + ((kq << 3) ^ (((j >> 3) & 7) << 4));
        *(v4h*)(wbuf + byo) = pv;
    }
    __syncthreads();

    const int rgrp = tid >> 4;
    const int joct = tid & 15;
    const int r0 = rgrp * 2;
    const int j0 = joct * 8;

    float a1[2][8];
#pragma unroll
    for (int rr = 0; rr < 2; ++rr)
#pragma unroll
        for (int jo = 0; jo < 8; ++jo) a1[rr][jo] = 0.f;

    for (int kc = 0; kc < 32; ++kc) {
        const int k = kc << 3;
        float pv[2][8];
#pragma unroll
        for (int rr = 0; rr < 2; ++rr) {
            const float4 pa = *(const float4*)&pooled[r0 + rr][k];
            const float4 pb = *(const float4*)&pooled[r0 + rr][k + 4];
            pv[rr][0] = pa.x; pv[rr][1] = pa.y; pv[rr][2] = pa.z; pv[rr][3] = pa.w;
            pv[rr][4] = pb.x; pv[rr][5] = pb.y; pv[rr][6] = pb.z; pv[rr][7] = pb.w;
        }
#pragma unroll
        for (int jo = 0; jo < 8; ++jo) {
            const int j = j0 + jo;
            const int byo = (j << 9) + ((k << 1) ^ (((j >> 3) & 7) << 4));
            const v8h wv = *(const v8h*)(wbuf + byo);
#pragma unroll
            for (int i = 0; i < 8; ++i) {
                const float wf = (float)wv[i];
#pragma unroll
                for (int rr = 0; rr < 2; ++rr)
                    a1[rr][jo] += pv[rr][i] * wf;
            }
        }
    }
#pragma unroll
    for (int rr = 0; rr < 2; ++rr)
#pragma unroll
        for (int jo = 0; jo < 8; ++jo) {
            const int j = j0 + jo;
            const float v = a1[rr][jo] + fc1b[j];
            h1s[r0 + rr][j] = v > 0.f ? v : 0.f;
        }
    __syncthreads();

    for (int i = tid; i < 100 * 32; i += 128) {
        const int j = i >> 5, kq = i & 31;
        const float4 v = *(const float4*)(fc2w + (size_t)j * 128 + (kq << 2));
        const int byo = (j << 9) + ((kq << 4) ^ (((j >> 3) & 7) << 4));
        *(float4*)(wbuf + byo) = v;
    }
    __syncthreads();

    if (j0 < 100) {
        float a2[2][8];
#pragma unroll
        for (int rr = 0; rr < 2; ++rr)
#pragma unroll
            for (int jo = 0; jo < 8; ++jo) a2[rr][jo] = 0.f;

        for (int kc = 0; kc < 16; ++kc) {
            const int k = kc << 3;
            float hv[2][8];
#pragma unroll
            for (int rr = 0; rr < 2; ++rr) {
                const float4 ha = *(const float4*)&h1s[r0 + rr][k];
                const float4 hbv = *(const float4*)&h1s[r0 + rr][k + 4];
                hv[rr][0] = ha.x; hv[rr][1] = ha.y; hv[rr][2] = ha.z; hv[rr][3] = ha.w;
                hv[rr][4] = hbv.x; hv[rr][5] = hbv.y; hv[rr][6] = hbv.z; hv[rr][7] = hbv.w;
            }
#pragma unroll
            for (int jo = 0; jo < 8; ++jo) {
                const int j = j0 + jo;
                if (j < 100) {
                    const int sw = ((j >> 3) & 7) << 4;
                    const float4 wa = *(const float4*)(wbuf + (j << 9) + ((k << 2) ^ sw));
                    const float4 wb = *(const float4*)(wbuf + (j << 9) + (((k + 4) << 2) ^ sw));
#pragma unroll
                    for (int rr = 0; rr < 2; ++rr) {
                        a2[rr][jo] += hv[rr][0] * wa.x + hv[rr][1] * wa.y
                                    + hv[rr][2] * wa.z + hv[rr][3] * wa.w
                                    + hv[rr][4] * wb.x + hv[rr][5] * wb.y
                                    + hv[rr][6] * wb.z + hv[rr][7] * wb.w;
                    }
                }
            }
        }
#pragma unroll
        for (int rr = 0; rr < 2; ++rr)
#pragma unroll
            for (int jo = 0; jo < 8; ++jo) {
                const int j = j0 + jo;
                if (j < 100)
                    out[(size_t)(rb + r0 + rr) * NCLS + j] = a2[rr][jo] + fc2b[j];
            }
    }
}

// ---------------------------------------------------------------------------
extern "C" void kernel_launch(void* const* d_in, const int* in_sizes, int n_in,
                              void* d_out, int out_size, void* d_ws, size_t ws_size,
                              hipStream_t stream)
{
    (void)in_sizes; (void)n_in; (void)out_size; (void)ws_size;
    const float* x    = (const float*)d_in[0];
    const float* wihf = (const float*)d_in[1];
    const float* whhf = (const float*)d_in[2];
    const float* bihf = (const float*)d_in[3];
    const float* bhhf = (const float*)d_in[4];
    const float* wihb = (const float*)d_in[5];
    const float* whhb = (const float*)d_in[6];
    const float* bihb = (const float*)d_in[7];
    const float* bhhb = (const float*)d_in[8];
    const float* fc1w = (const float*)d_in[9];
    const float* fc1b = (const float*)d_in[10];
    const float* fc2w = (const float*)d_in[11];
    const float* fc2b = (const float*)d_in[12];
    float* out = (float*)d_out;

    char* ws = (char*)d_ws;
    float*     hs    = (float*)ws;                                    // 4 MB
    size_t off = (size_t)4 * 1024 * 1024;
    _Float16*  xh    = (_Float16*)(ws + off); off += (size_t)NB * NT * NK * 2; // 100.7 MB
    _Float16*  wh    = (_Float16*)(ws + off); off += (size_t)2 * NG * NK * 2;
    _Float16*  whh_h = (_Float16*)(ws + off); off += (size_t)2 * NG * NH * 2;
    _Float16*  wh3   = (_Float16*)(ws + off); off += (size_t)2 * 128 * NK * 2;
    _Float16*  whh3  = (_Float16*)(ws + off); off += (size_t)2 * 128 * NH * 2;
    float*     bsum  = (float*)(ws + off);    off += 1024 * 4;

    k_prep<<<dim3(NB + 167), dim3(256), 0, stream>>>(
        x, wihf, wihb, whhf, whhb, bihf, bhhf, bihb, bhhb,
        xh, wh, whh_h, wh3, whh3, bsum);
    k_fused<<<dim3(128, 2), dim3(512), 0, stream>>>(
        xh, wh, whh_h, wh3, whh3, bsum, hs);
    k_head<<<dim3(256), dim3(128), 0, stream>>>(hs, fc1w, fc1b, fc2w, fc2b, out);
}